// Round 5
// baseline (504.972 us; speedup 1.0000x reference)
//
#include <hip/hip_runtime.h>
#include <hip/hip_bf16.h>

#define Nn 4096
#define Fdim 256
#define Ddim 128
#define NH 3

typedef __bf16 bf16x8 __attribute__((ext_vector_type(8)));
typedef float f32x4 __attribute__((ext_vector_type(4)));
typedef unsigned short ushort8v __attribute__((ext_vector_type(8)));
typedef unsigned short ushort4v __attribute__((ext_vector_type(4)));

#define MFMA(a, b, c) __builtin_amdgcn_mfma_f32_16x16x32_bf16((a), (b), (c), 0, 0, 0)

__device__ __forceinline__ float bf2f(unsigned short u) {
    union { unsigned int i; float f; } cv;
    cv.i = ((unsigned int)u) << 16;
    return cv.f;
}
__device__ __forceinline__ unsigned short f2bf(float f) {
    union { __bf16 b; unsigned short u; } cv;
    cv.b = (__bf16)f;
    return cv.u;
}
__device__ __forceinline__ bf16x8 cvt8(const float* p, float s) {
    const float4 lo = *(const float4*)p;
    const float4 hi = *(const float4*)(p + 4);
    bf16x8 r;
    r[0] = (__bf16)(lo.x * s); r[1] = (__bf16)(lo.y * s);
    r[2] = (__bf16)(lo.z * s); r[3] = (__bf16)(lo.w * s);
    r[4] = (__bf16)(hi.x * s); r[5] = (__bf16)(hi.y * s);
    r[6] = (__bf16)(hi.z * s); r[7] = (__bf16)(hi.w * s);
    return r;
}

// ---------------- KP: dtype probe (bf16 vs f32 inputs); zero-inits s[128] and ctr[32].
__global__ void kprobe(const unsigned short* __restrict__ X, float* __restrict__ mode,
                       float* __restrict__ s, int* __restrict__ ctr) {
    int t = threadIdx.x;  // 64 threads, 1 block
    s[t] = 0.f;
    s[t + 64] = 0.f;
    if (t < 32) ctr[t] = 0;
    int wild = 0;
    for (int i = t; i < 2048; i += 64) {
        unsigned short u = X[i];
        int e = (u >> 7) & 0xFF;
        if (e >= 132) wild = 1;
    }
    unsigned long long m = __ballot(wild != 0);
    if (t == 0) mode[0] = (__popcll(m) > 4) ? 0.0f : 1.0f;  // 1.0 => inputs are bf16
}

// ---------------- K0: W/kernels ([4][256][128] -> WT [4][128][256] bf16)
__global__ void k0_wt(const void* __restrict__ W_emb, const void* __restrict__ kernels,
                      unsigned short* __restrict__ WT, const float* __restrict__ mode) {
    bool isbf = mode[0] > 0.5f;
    int b = blockIdx.x, nt = b >> 1, fh = b & 1;
    __shared__ unsigned short T[128][136];
    int t = threadIdx.x;
    int d4 = t & 31, fr = t >> 5;
    if (isbf) {
        const unsigned short* Wsrc = (nt == 0) ? (const unsigned short*)W_emb
                                               : ((const unsigned short*)kernels + (size_t)(nt - 1) * Fdim * Ddim);
        for (int p = 0; p < 16; ++p) {
            int fl = fr + 8 * p;
            int f = fh * 128 + fl;
            ushort4v v = *(const ushort4v*)(Wsrc + (size_t)f * Ddim + 4 * d4);
            T[4 * d4 + 0][fl] = v[0]; T[4 * d4 + 1][fl] = v[1];
            T[4 * d4 + 2][fl] = v[2]; T[4 * d4 + 3][fl] = v[3];
        }
    } else {
        const float* Wsrc = (nt == 0) ? (const float*)W_emb
                                      : ((const float*)kernels + (size_t)(nt - 1) * Fdim * Ddim);
        for (int p = 0; p < 16; ++p) {
            int fl = fr + 8 * p;
            int f = fh * 128 + fl;
            float4 v = *(const float4*)(Wsrc + (size_t)f * Ddim + 4 * d4);
            T[4 * d4 + 0][fl] = f2bf(v.x); T[4 * d4 + 1][fl] = f2bf(v.y);
            T[4 * d4 + 2][fl] = f2bf(v.z); T[4 * d4 + 3][fl] = f2bf(v.w);
        }
    }
    __syncthreads();
    int f4 = t & 31, dr = t >> 5;
    for (int p = 0; p < 16; ++p) {
        int dd = dr + 8 * p;
        ushort4v w;
        w[0] = T[dd][4 * f4 + 0]; w[1] = T[dd][4 * f4 + 1];
        w[2] = T[dd][4 * f4 + 2]; w[3] = T[dd][4 * f4 + 3];
        *(ushort4v*)(WT + (size_t)nt * Ddim * Fdim + (size_t)dd * Fdim + fh * 128 + 4 * f4) = w;
    }
}

// ---------------- K1: fused projection: [E | XK0 | XK1 | XK2] = X @ [W_emb | k0 | k1 | k2]
// nt==0 blocks also contribute E column-sums to s via cross-lane reduce + atomics.
__global__ void k1_proj(const void* __restrict__ Xv, const unsigned short* __restrict__ WT,
                        float* __restrict__ E, float* __restrict__ XK, float* __restrict__ s,
                        const float* __restrict__ mode) {
    bool isbf = mode[0] > 0.5f;
    int mt = blockIdx.x >> 2, nt = blockIdx.x & 3;
    int t = threadIdx.x, wid = t >> 6, lane = t & 63, l15 = lane & 15, q = lane >> 4;
    int m0 = mt * 16;
    const unsigned short* BT = WT + (size_t)nt * Ddim * Fdim;
    const unsigned short* b0p = BT + (size_t)(wid * 32 + l15) * Fdim;
    const unsigned short* b1p = b0p + 16 * Fdim;
    f32x4 acc0 = {0.f, 0.f, 0.f, 0.f}, acc1 = {0.f, 0.f, 0.f, 0.f};
    if (isbf) {
        const unsigned short* Arow = (const unsigned short*)Xv + (size_t)(m0 + l15) * Fdim;
#pragma unroll
        for (int ks = 0; ks < 8; ++ks) {
            int kk = ks * 32 + q * 8;
            bf16x8 a = *(const bf16x8*)(Arow + kk);
            bf16x8 b0 = *(const bf16x8*)(b0p + kk);
            bf16x8 b1 = *(const bf16x8*)(b1p + kk);
            acc0 = MFMA(a, b0, acc0);
            acc1 = MFMA(a, b1, acc1);
        }
    } else {
        const float* Arow = (const float*)Xv + (size_t)(m0 + l15) * Fdim;
#pragma unroll
        for (int ks = 0; ks < 8; ++ks) {
            int kk = ks * 32 + q * 8;
            bf16x8 a = cvt8(Arow + kk, 1.0f);
            bf16x8 b0 = *(const bf16x8*)(b0p + kk);
            bf16x8 b1 = *(const bf16x8*)(b1p + kk);
            acc0 = MFMA(a, b0, acc0);
            acc1 = MFMA(a, b1, acc1);
        }
    }
    float* dst = (nt == 0) ? E : (XK + (size_t)(nt - 1) * Nn * Ddim);
#pragma unroll
    for (int r = 0; r < 4; ++r) {
        int ml = q * 4 + r;
        dst[(size_t)(m0 + ml) * Ddim + wid * 32 + l15] = acc0[r];
        dst[(size_t)(m0 + ml) * Ddim + wid * 32 + 16 + l15] = acc1[r];
    }
    if (nt == 0) {
        float c0 = acc0[0] + acc0[1] + acc0[2] + acc0[3];
        float c1 = acc1[0] + acc1[1] + acc1[2] + acc1[3];
        c0 += __shfl_xor(c0, 16, 64); c0 += __shfl_xor(c0, 32, 64);
        c1 += __shfl_xor(c1, 16, 64); c1 += __shfl_xor(c1, 32, 64);
        if (q == 0) {
            atomicAdd(&s[wid * 32 + l15], c0);
            atomicAdd(&s[wid * 32 + 16 + l15], c1);
        }
    }
}

// ---------------- K2: rowsums of adj [3*4096 rows], one wave per row
__global__ void k2_rowsum(const void* __restrict__ adjv, float* __restrict__ rowsum,
                          const float* __restrict__ mode) {
    bool isbf = mode[0] > 0.5f;
    int t = threadIdx.x, w = t >> 6, lane = t & 63;
    int r = blockIdx.x * 4 + w;
    float sum = 0.f;
    if (isbf) {
        const unsigned short* rp = (const unsigned short*)adjv + (size_t)r * Nn;
#pragma unroll
        for (int it = 0; it < 8; ++it) {
            ushort8v v = *(const ushort8v*)(rp + (it * 64 + lane) * 8);
            sum += bf2f(v[0]) + bf2f(v[1]) + bf2f(v[2]) + bf2f(v[3]) +
                   bf2f(v[4]) + bf2f(v[5]) + bf2f(v[6]) + bf2f(v[7]);
        }
    } else {
        const float4* rp = (const float4*)((const float*)adjv + (size_t)r * Nn);
#pragma unroll
        for (int it = 0; it < 16; ++it) {
            float4 v = rp[it * 64 + lane];
            sum += v.x + v.y + v.z + v.w;
        }
    }
#pragma unroll
    for (int off = 32; off > 0; off >>= 1) sum += __shfl_down(sum, off, 64);
    if (lane == 0) rowsum[r] = sum;
}

// ---------------- K4: d[h][i] = rsqrt(rowsum_adj[h][i] + alpha * dot(E[i], s))
__global__ void k4_dgen(const float* __restrict__ E, const float* __restrict__ rowsum,
                        const float* __restrict__ s, const void* __restrict__ alphap,
                        float* __restrict__ dbuf, const float* __restrict__ mode) {
    bool isbf = mode[0] > 0.5f;
    __shared__ float ss[128];
    int t = threadIdx.x;
    if (t < 128) ss[t] = s[t];
    __syncthreads();
    int wid = t >> 6, lane = t & 63;
    int node = blockIdx.x * 32 + wid * 8 + (lane >> 3);
    int sub = lane & 7;
    const float4* er = (const float4*)(E + (size_t)node * Ddim + sub * 16);
    float acc = 0.f;
#pragma unroll
    for (int k = 0; k < 4; ++k) {
        float4 v = er[k];
        int c = sub * 16 + 4 * k;
        acc += v.x * ss[c] + v.y * ss[c + 1] + v.z * ss[c + 2] + v.w * ss[c + 3];
    }
#pragma unroll
    for (int off = 1; off < 8; off <<= 1) acc += __shfl_xor(acc, off, 64);
    if (sub == 0) {
        float a = isbf ? bf2f(((const unsigned short*)alphap)[0]) : ((const float*)alphap)[0];
#pragma unroll
        for (int h = 0; h < NH; ++h)
            dbuf[h * Nn + node] = rsqrtf(rowsum[h * Nn + node] + a * acc);
    }
}

// ---------------- K5: build Y^T[h][n][j] = bf16(d_h[j]*XK[h][j][n]) row-major [128][4096]
// and row-major ET[d][j] = bf16(E[j][d]). 256 blocks (192 Y tiles + 64 ET tiles of 64 nodes).
__global__ void k5_transpose(const float* __restrict__ XK, const float* __restrict__ E,
                             const float* __restrict__ dbuf, unsigned short* __restrict__ Yp,
                             unsigned short* __restrict__ ET) {
    __shared__ unsigned short T[128][72];
    __shared__ float sl[64];
    int b = blockIdx.x, t = threadIdx.x;
    bool isET = (b >= 192);
    int h = 0, jt;
    const float* src;
    if (!isET) { h = b >> 6; jt = b & 63; src = XK + (size_t)h * Nn * Ddim; }
    else { jt = b - 192; src = E; }
    if (t < 64) sl[t] = isET ? 1.0f : dbuf[h * Nn + jt * 64 + t];
    __syncthreads();
    int d4 = t & 31, jr = t >> 5;
    for (int p = 0; p < 8; ++p) {
        int j = jr + 8 * p;  // 0..63
        float4 v = *(const float4*)(src + (size_t)(jt * 64 + j) * Ddim + 4 * d4);
        float sc = sl[j];
        T[4 * d4 + 0][j] = f2bf(v.x * sc); T[4 * d4 + 1][j] = f2bf(v.y * sc);
        T[4 * d4 + 2][j] = f2bf(v.z * sc); T[4 * d4 + 3][j] = f2bf(v.w * sc);
    }
    __syncthreads();
    int jj4 = t & 15, nr = t >> 4;
    unsigned short* dst = isET ? ET : (Yp + (size_t)h * Ddim * Nn);
    for (int p = 0; p < 8; ++p) {
        int n = nr + 16 * p;  // 0..127
        ushort4v w;
        w[0] = T[n][4 * jj4 + 0]; w[1] = T[n][4 * jj4 + 1];
        w[2] = T[n][4 * jj4 + 2]; w[3] = T[n][4 * jj4 + 3];
        int j = jt * 64 + 4 * jj4;
        *(ushort4v*)(dst + (size_t)n * Nn + j) = w;
    }
}

// ---------------- K6: Mpart[kc][h] = (E^T @ Y_h) partial over K-chunk (Y^T row-major)
__global__ void k6_mgen(const unsigned short* __restrict__ ET,
                        const unsigned short* __restrict__ Yp, float* __restrict__ Mpart) {
    int b = blockIdx.x;
    int kc = b / 24, rem = b % 24, h = rem >> 3, mtm = rem & 7;
    int t = threadIdx.x, wid = t >> 6, lane = t & 63, l15 = lane & 15, q = lane >> 4;
    int m0 = mtm * 16;
    const unsigned short* Ar = ET + (size_t)(m0 + l15) * Nn + kc * 512;
    const unsigned short* Yph = Yp + (size_t)h * Ddim * Nn;
    const unsigned short* bb = Yph + (size_t)(wid * 32 + l15) * Nn + kc * 512 + q * 8;
    f32x4 acc0 = {0.f, 0.f, 0.f, 0.f}, acc1 = {0.f, 0.f, 0.f, 0.f};
#pragma unroll 4
    for (int ks = 0; ks < 16; ++ks) {
        bf16x8 a = *(const bf16x8*)(Ar + ks * 32 + q * 8);
        bf16x8 b0 = *(const bf16x8*)(bb + ks * 32);
        bf16x8 b1 = *(const bf16x8*)(bb + (size_t)16 * Nn + ks * 32);
        acc0 = MFMA(a, b0, acc0);
        acc1 = MFMA(a, b1, acc1);
    }
    float* out = Mpart + (size_t)kc * (NH * Ddim * Ddim) + (size_t)h * (Ddim * Ddim);
#pragma unroll
    for (int r = 0; r < 4; ++r) {
        int ml = q * 4 + r;
        out[(m0 + ml) * Ddim + wid * 32 + l15] = acc0[r];
        out[(m0 + ml) * Ddim + wid * 32 + 16 + l15] = acc1[r];
    }
}

// ---------------- K6b: reduce 8 K-chunks and transpose: MT[d2][h*128+d1] bf16
__global__ void k6b_mred(const float* __restrict__ Mpart, unsigned short* __restrict__ MT) {
    int idx = blockIdx.x * 256 + threadIdx.x;  // < 49152
    int d2 = idx / 384, kcol = idx % 384;
    int h = kcol >> 7, d1 = kcol & 127;
    float sum = 0.f;
#pragma unroll
    for (int kc = 0; kc < 8; ++kc)
        sum += Mpart[(size_t)kc * (NH * Ddim * Ddim) + h * (Ddim * Ddim) + d1 * Ddim + d2];
    MT[idx] = f2bf(sum);
}

// ---------------- K8: L = sum_h alpha*d_h[i] * (E @ M_h), MFMA over K=384
__global__ void k8_lgen(const float* __restrict__ E, const float* __restrict__ dbuf,
                        const void* __restrict__ alphap, const unsigned short* __restrict__ MT,
                        float* __restrict__ L, const float* __restrict__ mode) {
    bool isbf = mode[0] > 0.5f;
    int mt = blockIdx.x;
    int t = threadIdx.x, wid = t >> 6, lane = t & 63, l15 = lane & 15, q = lane >> 4;
    int m0 = mt * 16, m = m0 + l15;
    float a = isbf ? bf2f(((const unsigned short*)alphap)[0]) : ((const float*)alphap)[0];
    float dv[NH];
#pragma unroll
    for (int h = 0; h < NH; ++h) dv[h] = a * dbuf[h * Nn + m];
    const float* Er = E + (size_t)m * Ddim;
    const unsigned short* b0p = MT + (size_t)(wid * 32 + l15) * 384;
    const unsigned short* b1p = b0p + 16 * 384;
    f32x4 acc0 = {0.f, 0.f, 0.f, 0.f}, acc1 = {0.f, 0.f, 0.f, 0.f};
#pragma unroll
    for (int ks = 0; ks < 12; ++ks) {
        int kk = ks * 32;
        int h = kk >> 7;
        int kloc = (kk & 127) + q * 8;
        bf16x8 aa = cvt8(Er + kloc, dv[h]);
        bf16x8 b0 = *(const bf16x8*)(b0p + kk + q * 8);
        bf16x8 b1 = *(const bf16x8*)(b1p + kk + q * 8);
        acc0 = MFMA(aa, b0, acc0);
        acc1 = MFMA(aa, b1, acc1);
    }
#pragma unroll
    for (int r = 0; r < 4; ++r) {
        int ml = q * 4 + r;
        L[(size_t)(m0 + ml) * Ddim + wid * 32 + l15] = acc0[r];
        L[(size_t)(m0 + ml) * Ddim + wid * 32 + 16 + l15] = acc1[r];
    }
}

// ---------------- K7: hop-merged, K-split main GEMM + fused final combine.
// Pp[kc][i,:] = sum_h d_h[i] * (adj_h @ Y_h)[i,:] over K-range kc*512..+512.
// Grid = 32 mtiles x 8 ksplits = 256 blocks x 512 threads (1 block/CU).
// 2-deep software pipeline: chunk c+2's global loads issued at top of iter c,
// chunk c+1's (landed) regs written to LDS after compute -> each load gets ~2
// compute phases of latency cover before its vmcnt wait. Double-buffered 96 KB
// LDS, XOR-swizzled 16B granules, 1 barrier/chunk.
// The 8th-finishing ksplit block per mtile (device-scope counter + fences)
// reduces the 8 Pp partials + L and writes relu'd output (replaces k9).
// No spin-wait anywhere -> no co-residency/dispatch-order assumptions (G16-safe).
__global__ void __launch_bounds__(512, 1) k7_fused(const void* __restrict__ adjv,
        const unsigned short* __restrict__ Yp, const float* __restrict__ dbuf,
        float* __restrict__ Pp, const float* __restrict__ L, void* __restrict__ outv,
        int* __restrict__ ctr, const float* __restrict__ mode) {
    bool isbf = mode[0] > 0.5f;
    __shared__ unsigned short lds[2][6][4096];  // [buf][A0 A1 A2 B0 B1 B2][128r x 32k] = 96 KB
    __shared__ float dsh[NH][128];
    __shared__ int lastFlag;
    int b = blockIdx.x;
    int mt = b >> 3, kc = b & 7;
    int m0 = mt * 128;
    int kbase = kc * 512;
    int t = threadIdx.x;
    if (t < 384) { int h = t >> 7, m = t & 127; dsh[h][m] = dbuf[h * Nn + m0 + m]; }

    // staging: granule t -> (row sr, slot ss); fetch swizzled k-slot sw = ss ^ ((sr>>2)&3)
    int sr = t >> 2, ss = t & 3;
    int sw = ss ^ ((sr >> 2) & 3);
    const float* aBaseF = (const float*)adjv + (size_t)(m0 + sr) * Nn + kbase + 8 * sw;
    const unsigned short* aBaseH = (const unsigned short*)adjv + (size_t)(m0 + sr) * Nn + kbase + 8 * sw;
    const unsigned short* bBase = Yp + (size_t)sr * Nn + kbase + 8 * sw;

    // wave tile: 8 waves as 4M x 2N; wave = 32 rows x 64 cols
    int wid = t >> 6, lane = t & 63, l15 = lane & 15, q = lane >> 4;
    int wm = wid >> 1, wn = wid & 1;
    f32x4 acc[NH][2][4] = {};

    // two named register staging sets (static indexing only — no runtime-indexed arrays)
    float4 AF0[NH][2], AF1[NH][2];
    ushort8v AH0[NH], AH1[NH], BR0[NH], BR1[NH];

    auto stage_load = [&](float4 (&AF)[NH][2], ushort8v (&AH)[NH], ushort8v (&BR)[NH], int c) {
        int ko = c * 32;
        if (isbf) {
#pragma unroll
            for (int h = 0; h < NH; ++h)
                AH[h] = *(const ushort8v*)(aBaseH + (size_t)h * Nn * Nn + ko);
        } else {
#pragma unroll
            for (int h = 0; h < NH; ++h) {
                AF[h][0] = *(const float4*)(aBaseF + (size_t)h * Nn * Nn + ko);
                AF[h][1] = *(const float4*)(aBaseF + (size_t)h * Nn * Nn + ko + 4);
            }
        }
#pragma unroll
        for (int h = 0; h < NH; ++h)
            BR[h] = *(const ushort8v*)(bBase + (size_t)h * Ddim * Nn + ko);
    };
    auto stage_write = [&](float4 (&AF)[NH][2], ushort8v (&AH)[NH], ushort8v (&BR)[NH], int buf) {
#pragma unroll
        for (int h = 0; h < NH; ++h) {
            ushort8v w;
            if (isbf) w = AH[h];
            else {
                w[0] = f2bf(AF[h][0].x); w[1] = f2bf(AF[h][0].y);
                w[2] = f2bf(AF[h][0].z); w[3] = f2bf(AF[h][0].w);
                w[4] = f2bf(AF[h][1].x); w[5] = f2bf(AF[h][1].y);
                w[6] = f2bf(AF[h][1].z); w[7] = f2bf(AF[h][1].w);
            }
            *(ushort8v*)&lds[buf][h][t * 8] = w;          // linear 16B granules, conflict-free
            *(ushort8v*)&lds[buf][3 + h][t * 8] = BR[h];
        }
    };
    auto compute = [&](int buf) {
#pragma unroll
        for (int h = 0; h < NH; ++h) {
            bf16x8 af[2], bfr[4];
#pragma unroll
            for (int i = 0; i < 2; ++i) {
                int m = wm * 32 + i * 16 + l15;
                af[i] = *(const bf16x8*)&lds[buf][h][m * 32 + (q ^ ((m >> 2) & 3)) * 8];
            }
#pragma unroll
            for (int j = 0; j < 4; ++j) {
                int n = wn * 64 + j * 16 + l15;
                bfr[j] = *(const bf16x8*)&lds[buf][3 + h][n * 32 + (q ^ ((n >> 2) & 3)) * 8];
            }
#pragma unroll
            for (int i = 0; i < 2; ++i)
#pragma unroll
                for (int j = 0; j < 4; ++j)
                    acc[h][i][j] = MFMA(af[i], bfr[j], acc[h][i][j]);
        }
    };

    // prologue: chunk0 -> set0 -> lds0; chunk1 -> set1 (left in flight)
    stage_load(AF0, AH0, BR0, 0);
    stage_load(AF1, AH1, BR1, 1);
    stage_write(AF0, AH0, BR0, 0);   // waits only set0's loads; set1 stays in flight
    __syncthreads();

    // main loop: 8 iterations x 2 chunks; each load issued 2 phases before its wait
    for (int cc = 0; cc < 8; ++cc) {
        int c0 = 2 * cc;
        // even chunk c0 (buf 0)
        if (cc < 7) stage_load(AF0, AH0, BR0, c0 + 2);
        compute(0);
        stage_write(AF1, AH1, BR1, 1);   // chunk c0+1 -> buf1 (loaded one full phase ago)
        __syncthreads();
        // odd chunk c0+1 (buf 1)
        if (cc < 7) stage_load(AF1, AH1, BR1, c0 + 3);
        compute(1);
        if (cc < 7) {
            stage_write(AF0, AH0, BR0, 0);  // chunk c0+2 -> buf0
            __syncthreads();
        }
    }

    // epilogue: per-hop row scale d_h[i], hop-sum, plain stores to this ksplit's partial
    float* Pk = Pp + (size_t)kc * (Nn * Ddim);
#pragma unroll
    for (int i = 0; i < 2; ++i) {
#pragma unroll
        for (int r = 0; r < 4; ++r) {
            int row = wm * 32 + i * 16 + q * 4 + r;
            float d0 = dsh[0][row], d1 = dsh[1][row], d2 = dsh[2][row];
            float* pr = Pk + (size_t)(m0 + row) * Ddim + wn * 64 + l15;
#pragma unroll
            for (int j = 0; j < 4; ++j) {
                float v = d0 * acc[0][i][j][r] + d1 * acc[1][i][j][r] + d2 * acc[2][i][j][r];
                pr[j * 16] = v;
            }
        }
    }

    // fused combine: last-finishing ksplit block for this mtile reduces partials + L
    __threadfence();                       // release: make our Pp stores visible
    if (t == 0) {
        int prev = atomicAdd(&ctr[mt], 1); // device-scope
        lastFlag = (prev == 7) ? 1 : 0;
    }
    __syncthreads();
    if (lastFlag) {
        __threadfence();                   // acquire: see other blocks' Pp stores
        int row = m0 + (t >> 2);
        int c0 = (t & 3) * 32;
#pragma unroll
        for (int g = 0; g < 8; ++g) {
            size_t off = (size_t)row * Ddim + c0 + g * 4;
            float4 a = *(const float4*)(L + off);
            float r0 = a.x, r1 = a.y, r2 = a.z, r3 = a.w;
#pragma unroll
            for (int k2 = 0; k2 < 8; ++k2) {
                float4 v = *(const float4*)(Pp + (size_t)k2 * (Nn * Ddim) + off);
                r0 += v.x; r1 += v.y; r2 += v.z; r3 += v.w;
            }
            r0 = r0 > 0.f ? r0 : 0.f;
            r1 = r1 > 0.f ? r1 : 0.f;
            r2 = r2 > 0.f ? r2 : 0.f;
            r3 = r3 > 0.f ? r3 : 0.f;
            if (isbf) {
                ushort4v w;
                w[0] = f2bf(r0); w[1] = f2bf(r1); w[2] = f2bf(r2); w[3] = f2bf(r3);
                *(ushort4v*)((unsigned short*)outv + off) = w;
            } else {
                float4 w; w.x = r0; w.y = r1; w.z = r2; w.w = r3;
                *(float4*)((float*)outv + off) = w;
            }
        }
    }
}

extern "C" void kernel_launch(void* const* d_in, const int* in_sizes, int n_in,
                              void* d_out, int out_size, void* d_ws, size_t ws_size,
                              hipStream_t stream) {
    const void* X = d_in[0];
    const void* adj = d_in[1];
    const void* W_emb = d_in[2];
    const void* kernels = d_in[3];
    const void* alphap = d_in[4];

    // workspace layout (~34 MB)
    float* E = (float*)d_ws;            // 524288 f32
    float* XK = E + 524288;             // 1572864 f32
    float* rowsum = XK + 1572864;       // 12288 f32
    float* s = rowsum + 12288;          // 128 f32
    float* dbuf = s + 128;              // 12288 f32
    float* Mpart = dbuf + 12288;        // 393216 f32
    float* L = Mpart + 393216;          // 524288 f32
    float* Pp = L + 524288;             // 8 x 524288 f32 (K-split partials)
    unsigned short* WT = (unsigned short*)(Pp + 8 * 524288);  // 131072 u16
    unsigned short* ET = WT + 131072;   // 524288 u16
    unsigned short* Yp = ET + 524288;   // 1572864 u16  (Y^T row-major [h][128][4096])
    unsigned short* MT = Yp + 1572864;  // 49152 u16
    float* modef = (float*)(MT + 49152);// 1 f32
    int* ctr = (int*)(modef + 1);       // 32 int (per-mtile completion counters)

    // Order: all X-side work BEFORE the adj sweep, so that between k2 (which pulls
    // 201 MB f32 adj through L3) and k7 (which re-reads it) only ~15 MB of small
    // tensors intervene -> maximize k7's L3 hit rate on adj.
    kprobe<<<1, 64, 0, stream>>>((const unsigned short*)X, modef, s, ctr);
    k0_wt<<<8, 256, 0, stream>>>(W_emb, kernels, WT, modef);
    k1_proj<<<1024, 256, 0, stream>>>(X, WT, E, XK, s, modef);  // + fused colsum
    k2_rowsum<<<3072, 256, 0, stream>>>(adj, rowsum, modef);
    k4_dgen<<<128, 256, 0, stream>>>(E, rowsum, s, alphap, dbuf, modef);
    k5_transpose<<<256, 256, 0, stream>>>(XK, E, dbuf, Yp, ET);
    k6_mgen<<<192, 256, 0, stream>>>(ET, Yp, Mpart);
    k6b_mred<<<192, 256, 0, stream>>>(Mpart, MT);
    k8_lgen<<<256, 256, 0, stream>>>(E, dbuf, alphap, MT, L, modef);
    k7_fused<<<256, 512, 0, stream>>>(adj, Yp, dbuf, Pp, L, d_out, ctr, modef);
}

// Round 6
// 384.301 us; speedup vs baseline: 1.3140x; 1.3140x over previous
//
#include <hip/hip_runtime.h>
#include <hip/hip_bf16.h>

#define Nn 4096
#define Fdim 256
#define Ddim 128
#define NH 3

typedef __bf16 bf16x8 __attribute__((ext_vector_type(8)));
typedef float f32x4 __attribute__((ext_vector_type(4)));
typedef unsigned short ushort8v __attribute__((ext_vector_type(8)));
typedef unsigned short ushort4v __attribute__((ext_vector_type(4)));

#define MFMA(a, b, c) __builtin_amdgcn_mfma_f32_16x16x32_bf16((a), (b), (c), 0, 0, 0)

__device__ __forceinline__ float bf2f(unsigned short u) {
    union { unsigned int i; float f; } cv;
    cv.i = ((unsigned int)u) << 16;
    return cv.f;
}
__device__ __forceinline__ unsigned short f2bf(float f) {
    union { __bf16 b; unsigned short u; } cv;
    cv.b = (__bf16)f;
    return cv.u;
}
__device__ __forceinline__ bf16x8 cvt8(const float* p, float s) {
    const float4 lo = *(const float4*)p;
    const float4 hi = *(const float4*)(p + 4);
    bf16x8 r;
    r[0] = (__bf16)(lo.x * s); r[1] = (__bf16)(lo.y * s);
    r[2] = (__bf16)(lo.z * s); r[3] = (__bf16)(lo.w * s);
    r[4] = (__bf16)(hi.x * s); r[5] = (__bf16)(hi.y * s);
    r[6] = (__bf16)(hi.z * s); r[7] = (__bf16)(hi.w * s);
    return r;
}

// ---------------- KP: dtype probe (bf16 vs f32 inputs); also zero-inits s[128].
__global__ void kprobe(const unsigned short* __restrict__ X, float* __restrict__ mode,
                       float* __restrict__ s) {
    int t = threadIdx.x;  // 64 threads, 1 block
    s[t] = 0.f;
    s[t + 64] = 0.f;
    int wild = 0;
    for (int i = t; i < 2048; i += 64) {
        unsigned short u = X[i];
        int e = (u >> 7) & 0xFF;
        if (e >= 132) wild = 1;
    }
    unsigned long long m = __ballot(wild != 0);
    if (t == 0) mode[0] = (__popcll(m) > 4) ? 0.0f : 1.0f;  // 1.0 => inputs are bf16
}

// ---------------- K0: W/kernels ([4][256][128] -> WT [4][128][256] bf16)
__global__ void k0_wt(const void* __restrict__ W_emb, const void* __restrict__ kernels,
                      unsigned short* __restrict__ WT, const float* __restrict__ mode) {
    bool isbf = mode[0] > 0.5f;
    int b = blockIdx.x, nt = b >> 1, fh = b & 1;
    __shared__ unsigned short T[128][136];
    int t = threadIdx.x;
    int d4 = t & 31, fr = t >> 5;
    if (isbf) {
        const unsigned short* Wsrc = (nt == 0) ? (const unsigned short*)W_emb
                                               : ((const unsigned short*)kernels + (size_t)(nt - 1) * Fdim * Ddim);
        for (int p = 0; p < 16; ++p) {
            int fl = fr + 8 * p;
            int f = fh * 128 + fl;
            ushort4v v = *(const ushort4v*)(Wsrc + (size_t)f * Ddim + 4 * d4);
            T[4 * d4 + 0][fl] = v[0]; T[4 * d4 + 1][fl] = v[1];
            T[4 * d4 + 2][fl] = v[2]; T[4 * d4 + 3][fl] = v[3];
        }
    } else {
        const float* Wsrc = (nt == 0) ? (const float*)W_emb
                                      : ((const float*)kernels + (size_t)(nt - 1) * Fdim * Ddim);
        for (int p = 0; p < 16; ++p) {
            int fl = fr + 8 * p;
            int f = fh * 128 + fl;
            float4 v = *(const float4*)(Wsrc + (size_t)f * Ddim + 4 * d4);
            T[4 * d4 + 0][fl] = f2bf(v.x); T[4 * d4 + 1][fl] = f2bf(v.y);
            T[4 * d4 + 2][fl] = f2bf(v.z); T[4 * d4 + 3][fl] = f2bf(v.w);
        }
    }
    __syncthreads();
    int f4 = t & 31, dr = t >> 5;
    for (int p = 0; p < 16; ++p) {
        int dd = dr + 8 * p;
        ushort4v w;
        w[0] = T[dd][4 * f4 + 0]; w[1] = T[dd][4 * f4 + 1];
        w[2] = T[dd][4 * f4 + 2]; w[3] = T[dd][4 * f4 + 3];
        *(ushort4v*)(WT + (size_t)nt * Ddim * Fdim + (size_t)dd * Fdim + fh * 128 + 4 * f4) = w;
    }
}

// ---------------- K1: fused projection: [E | XK0 | XK1 | XK2] = X @ [W_emb | k0 | k1 | k2]
// nt==0 blocks also contribute E column-sums to s via cross-lane reduce + atomics.
__global__ void k1_proj(const void* __restrict__ Xv, const unsigned short* __restrict__ WT,
                        float* __restrict__ E, float* __restrict__ XK, float* __restrict__ s,
                        const float* __restrict__ mode) {
    bool isbf = mode[0] > 0.5f;
    int mt = blockIdx.x >> 2, nt = blockIdx.x & 3;
    int t = threadIdx.x, wid = t >> 6, lane = t & 63, l15 = lane & 15, q = lane >> 4;
    int m0 = mt * 16;
    const unsigned short* BT = WT + (size_t)nt * Ddim * Fdim;
    const unsigned short* b0p = BT + (size_t)(wid * 32 + l15) * Fdim;
    const unsigned short* b1p = b0p + 16 * Fdim;
    f32x4 acc0 = {0.f, 0.f, 0.f, 0.f}, acc1 = {0.f, 0.f, 0.f, 0.f};
    if (isbf) {
        const unsigned short* Arow = (const unsigned short*)Xv + (size_t)(m0 + l15) * Fdim;
#pragma unroll
        for (int ks = 0; ks < 8; ++ks) {
            int kk = ks * 32 + q * 8;
            bf16x8 a = *(const bf16x8*)(Arow + kk);
            bf16x8 b0 = *(const bf16x8*)(b0p + kk);
            bf16x8 b1 = *(const bf16x8*)(b1p + kk);
            acc0 = MFMA(a, b0, acc0);
            acc1 = MFMA(a, b1, acc1);
        }
    } else {
        const float* Arow = (const float*)Xv + (size_t)(m0 + l15) * Fdim;
#pragma unroll
        for (int ks = 0; ks < 8; ++ks) {
            int kk = ks * 32 + q * 8;
            bf16x8 a = cvt8(Arow + kk, 1.0f);
            bf16x8 b0 = *(const bf16x8*)(b0p + kk);
            bf16x8 b1 = *(const bf16x8*)(b1p + kk);
            acc0 = MFMA(a, b0, acc0);
            acc1 = MFMA(a, b1, acc1);
        }
    }
    float* dst = (nt == 0) ? E : (XK + (size_t)(nt - 1) * Nn * Ddim);
#pragma unroll
    for (int r = 0; r < 4; ++r) {
        int ml = q * 4 + r;
        dst[(size_t)(m0 + ml) * Ddim + wid * 32 + l15] = acc0[r];
        dst[(size_t)(m0 + ml) * Ddim + wid * 32 + 16 + l15] = acc1[r];
    }
    if (nt == 0) {
        float c0 = acc0[0] + acc0[1] + acc0[2] + acc0[3];
        float c1 = acc1[0] + acc1[1] + acc1[2] + acc1[3];
        c0 += __shfl_xor(c0, 16, 64); c0 += __shfl_xor(c0, 32, 64);
        c1 += __shfl_xor(c1, 16, 64); c1 += __shfl_xor(c1, 32, 64);
        if (q == 0) {
            atomicAdd(&s[wid * 32 + l15], c0);
            atomicAdd(&s[wid * 32 + 16 + l15], c1);
        }
    }
}

// ---------------- K2: rowsums of adj [3*4096 rows], one wave per row
__global__ void k2_rowsum(const void* __restrict__ adjv, float* __restrict__ rowsum,
                          const float* __restrict__ mode) {
    bool isbf = mode[0] > 0.5f;
    int t = threadIdx.x, w = t >> 6, lane = t & 63;
    int r = blockIdx.x * 4 + w;
    float sum = 0.f;
    if (isbf) {
        const unsigned short* rp = (const unsigned short*)adjv + (size_t)r * Nn;
#pragma unroll
        for (int it = 0; it < 8; ++it) {
            ushort8v v = *(const ushort8v*)(rp + (it * 64 + lane) * 8);
            sum += bf2f(v[0]) + bf2f(v[1]) + bf2f(v[2]) + bf2f(v[3]) +
                   bf2f(v[4]) + bf2f(v[5]) + bf2f(v[6]) + bf2f(v[7]);
        }
    } else {
        const float4* rp = (const float4*)((const float*)adjv + (size_t)r * Nn);
#pragma unroll
        for (int it = 0; it < 16; ++it) {
            float4 v = rp[it * 64 + lane];
            sum += v.x + v.y + v.z + v.w;
        }
    }
#pragma unroll
    for (int off = 32; off > 0; off >>= 1) sum += __shfl_down(sum, off, 64);
    if (lane == 0) rowsum[r] = sum;
}

// ---------------- K4: d[h][i] = rsqrt(rowsum_adj[h][i] + alpha * dot(E[i], s))
__global__ void k4_dgen(const float* __restrict__ E, const float* __restrict__ rowsum,
                        const float* __restrict__ s, const void* __restrict__ alphap,
                        float* __restrict__ dbuf, const float* __restrict__ mode) {
    bool isbf = mode[0] > 0.5f;
    __shared__ float ss[128];
    int t = threadIdx.x;
    if (t < 128) ss[t] = s[t];
    __syncthreads();
    int wid = t >> 6, lane = t & 63;
    int node = blockIdx.x * 32 + wid * 8 + (lane >> 3);
    int sub = lane & 7;
    const float4* er = (const float4*)(E + (size_t)node * Ddim + sub * 16);
    float acc = 0.f;
#pragma unroll
    for (int k = 0; k < 4; ++k) {
        float4 v = er[k];
        int c = sub * 16 + 4 * k;
        acc += v.x * ss[c] + v.y * ss[c + 1] + v.z * ss[c + 2] + v.w * ss[c + 3];
    }
#pragma unroll
    for (int off = 1; off < 8; off <<= 1) acc += __shfl_xor(acc, off, 64);
    if (sub == 0) {
        float a = isbf ? bf2f(((const unsigned short*)alphap)[0]) : ((const float*)alphap)[0];
#pragma unroll
        for (int h = 0; h < NH; ++h)
            dbuf[h * Nn + node] = rsqrtf(rowsum[h * Nn + node] + a * acc);
    }
}

// ---------------- K5: build Y^T[h][n][j] = bf16(d_h[j]*XK[h][j][n]) row-major [128][4096]
// and row-major ET[d][j] = bf16(E[j][d]). 256 blocks (192 Y tiles + 64 ET tiles of 64 nodes).
__global__ void k5_transpose(const float* __restrict__ XK, const float* __restrict__ E,
                             const float* __restrict__ dbuf, unsigned short* __restrict__ Yp,
                             unsigned short* __restrict__ ET) {
    __shared__ unsigned short T[128][72];
    __shared__ float sl[64];
    int b = blockIdx.x, t = threadIdx.x;
    bool isET = (b >= 192);
    int h = 0, jt;
    const float* src;
    if (!isET) { h = b >> 6; jt = b & 63; src = XK + (size_t)h * Nn * Ddim; }
    else { jt = b - 192; src = E; }
    if (t < 64) sl[t] = isET ? 1.0f : dbuf[h * Nn + jt * 64 + t];
    __syncthreads();
    int d4 = t & 31, jr = t >> 5;
    for (int p = 0; p < 8; ++p) {
        int j = jr + 8 * p;  // 0..63
        float4 v = *(const float4*)(src + (size_t)(jt * 64 + j) * Ddim + 4 * d4);
        float sc = sl[j];
        T[4 * d4 + 0][j] = f2bf(v.x * sc); T[4 * d4 + 1][j] = f2bf(v.y * sc);
        T[4 * d4 + 2][j] = f2bf(v.z * sc); T[4 * d4 + 3][j] = f2bf(v.w * sc);
    }
    __syncthreads();
    int jj4 = t & 15, nr = t >> 4;
    unsigned short* dst = isET ? ET : (Yp + (size_t)h * Ddim * Nn);
    for (int p = 0; p < 8; ++p) {
        int n = nr + 16 * p;  // 0..127
        ushort4v w;
        w[0] = T[n][4 * jj4 + 0]; w[1] = T[n][4 * jj4 + 1];
        w[2] = T[n][4 * jj4 + 2]; w[3] = T[n][4 * jj4 + 3];
        int j = jt * 64 + 4 * jj4;
        *(ushort4v*)(dst + (size_t)n * Nn + j) = w;
    }
}

// ---------------- K6: Mpart[kc][h] = (E^T @ Y_h) partial over K-chunk (Y^T row-major)
__global__ void k6_mgen(const unsigned short* __restrict__ ET,
                        const unsigned short* __restrict__ Yp, float* __restrict__ Mpart) {
    int b = blockIdx.x;
    int kc = b / 24, rem = b % 24, h = rem >> 3, mtm = rem & 7;
    int t = threadIdx.x, wid = t >> 6, lane = t & 63, l15 = lane & 15, q = lane >> 4;
    int m0 = mtm * 16;
    const unsigned short* Ar = ET + (size_t)(m0 + l15) * Nn + kc * 512;
    const unsigned short* Yph = Yp + (size_t)h * Ddim * Nn;
    const unsigned short* bb = Yph + (size_t)(wid * 32 + l15) * Nn + kc * 512 + q * 8;
    f32x4 acc0 = {0.f, 0.f, 0.f, 0.f}, acc1 = {0.f, 0.f, 0.f, 0.f};
#pragma unroll 4
    for (int ks = 0; ks < 16; ++ks) {
        bf16x8 a = *(const bf16x8*)(Ar + ks * 32 + q * 8);
        bf16x8 b0 = *(const bf16x8*)(bb + ks * 32);
        bf16x8 b1 = *(const bf16x8*)(bb + (size_t)16 * Nn + ks * 32);
        acc0 = MFMA(a, b0, acc0);
        acc1 = MFMA(a, b1, acc1);
    }
    float* out = Mpart + (size_t)kc * (NH * Ddim * Ddim) + (size_t)h * (Ddim * Ddim);
#pragma unroll
    for (int r = 0; r < 4; ++r) {
        int ml = q * 4 + r;
        out[(m0 + ml) * Ddim + wid * 32 + l15] = acc0[r];
        out[(m0 + ml) * Ddim + wid * 32 + 16 + l15] = acc1[r];
    }
}

// ---------------- K6b: reduce 8 K-chunks and transpose: MT[d2][h*128+d1] bf16
__global__ void k6b_mred(const float* __restrict__ Mpart, unsigned short* __restrict__ MT) {
    int idx = blockIdx.x * 256 + threadIdx.x;  // < 49152
    int d2 = idx / 384, kcol = idx % 384;
    int h = kcol >> 7, d1 = kcol & 127;
    float sum = 0.f;
#pragma unroll
    for (int kc = 0; kc < 8; ++kc)
        sum += Mpart[(size_t)kc * (NH * Ddim * Ddim) + h * (Ddim * Ddim) + d1 * Ddim + d2];
    MT[idx] = f2bf(sum);
}

// ---------------- K8: L = sum_h alpha*d_h[i] * (E @ M_h), MFMA over K=384
__global__ void k8_lgen(const float* __restrict__ E, const float* __restrict__ dbuf,
                        const void* __restrict__ alphap, const unsigned short* __restrict__ MT,
                        float* __restrict__ L, const float* __restrict__ mode) {
    bool isbf = mode[0] > 0.5f;
    int mt = blockIdx.x;
    int t = threadIdx.x, wid = t >> 6, lane = t & 63, l15 = lane & 15, q = lane >> 4;
    int m0 = mt * 16, m = m0 + l15;
    float a = isbf ? bf2f(((const unsigned short*)alphap)[0]) : ((const float*)alphap)[0];
    float dv[NH];
#pragma unroll
    for (int h = 0; h < NH; ++h) dv[h] = a * dbuf[h * Nn + m];
    const float* Er = E + (size_t)m * Ddim;
    const unsigned short* b0p = MT + (size_t)(wid * 32 + l15) * 384;
    const unsigned short* b1p = b0p + 16 * 384;
    f32x4 acc0 = {0.f, 0.f, 0.f, 0.f}, acc1 = {0.f, 0.f, 0.f, 0.f};
#pragma unroll
    for (int ks = 0; ks < 12; ++ks) {
        int kk = ks * 32;
        int h = kk >> 7;
        int kloc = (kk & 127) + q * 8;
        bf16x8 aa = cvt8(Er + kloc, dv[h]);
        bf16x8 b0 = *(const bf16x8*)(b0p + kk + q * 8);
        bf16x8 b1 = *(const bf16x8*)(b1p + kk + q * 8);
        acc0 = MFMA(aa, b0, acc0);
        acc1 = MFMA(aa, b1, acc1);
    }
#pragma unroll
    for (int r = 0; r < 4; ++r) {
        int ml = q * 4 + r;
        L[(size_t)(m0 + ml) * Ddim + wid * 32 + l15] = acc0[r];
        L[(size_t)(m0 + ml) * Ddim + wid * 32 + 16 + l15] = acc1[r];
    }
}

// ---------------- K7: hop-merged, K-split main GEMM — R3 core, 2-blocks/CU geometry.
// Pp[kc][i,:] = sum_h d_h[i] * (adj_h @ Y_h)[i,:] over K-range kc*512..+512.
// Grid = 64 mtiles (64 rows) x 8 ksplits = 512 blocks x 256 threads, LDS 72 KB
// -> 2 blocks/CU: while one block drains vmcnt at its barrier, the other's waves
// compute (cross-block latency overlap; R5's 1-block/CU had none).
// Single register staging set (R5's dual-set 128-VGPR cap serialized loads — reverted).
// 1-deep issue-early/write-late, 1 barrier/chunk, XOR-swizzled 16B granules.
__global__ void __launch_bounds__(256, 2) k7_fused(const void* __restrict__ adjv,
        const unsigned short* __restrict__ Yp, const float* __restrict__ dbuf,
        float* __restrict__ Pp, const float* __restrict__ mode) {
    bool isbf = mode[0] > 0.5f;
    __shared__ unsigned short Alds[2][NH][64 * 32];   // 24 KB
    __shared__ unsigned short Blds[2][NH][128 * 32];  // 48 KB
    __shared__ float dsh[NH][64];
    int b = blockIdx.x;
    int mt = b >> 3, kc = b & 7;
    int m0 = mt * 64;
    int kbase = kc * 512;
    int t = threadIdx.x;
    if (t < 192) { int h = t >> 6, m = t & 63; dsh[h][m] = dbuf[h * Nn + m0 + m]; }

    // staging: granule t -> (row sr, slot ss); fetch swizzled k-slot sw = ss ^ ((sr>>2)&3)
    int sr = t >> 2, ss = t & 3;
    int sw = ss ^ ((sr >> 2) & 3);
    const float* aBaseF = (const float*)adjv + (size_t)(m0 + sr) * Nn + kbase + 8 * sw;
    const unsigned short* aBaseH = (const unsigned short*)adjv + (size_t)(m0 + sr) * Nn + kbase + 8 * sw;
    // B rows: pass0 = sr, pass1 = sr+64; (sr+64)>>2 & 3 == sr>>2 & 3, so same swizzle.
    const unsigned short* bBase = Yp + (size_t)sr * Nn + kbase + 8 * sw;

    // wave tile: 4 waves as 2M x 2N; wave = 32 rows x 64 cols
    int wid = t >> 6, lane = t & 63, l15 = lane & 15, q = lane >> 4;
    int wm = wid >> 1, wn = wid & 1;
    f32x4 acc[NH][2][4] = {};

    float4 AF[NH][2];
    ushort8v AH[NH];
    ushort8v BR[NH][2];

    auto stage_load = [&](int c) {
        int ko = c * 32;
        if (isbf) {
#pragma unroll
            for (int h = 0; h < NH; ++h)
                AH[h] = *(const ushort8v*)(aBaseH + (size_t)h * Nn * Nn + ko);
        } else {
#pragma unroll
            for (int h = 0; h < NH; ++h) {
                AF[h][0] = *(const float4*)(aBaseF + (size_t)h * Nn * Nn + ko);
                AF[h][1] = *(const float4*)(aBaseF + (size_t)h * Nn * Nn + ko + 4);
            }
        }
#pragma unroll
        for (int h = 0; h < NH; ++h) {
            BR[h][0] = *(const ushort8v*)(bBase + (size_t)h * Ddim * Nn + ko);
            BR[h][1] = *(const ushort8v*)(bBase + (size_t)h * Ddim * Nn + (size_t)64 * Nn + ko);
        }
    };
    auto stage_write = [&](int buf) {
#pragma unroll
        for (int h = 0; h < NH; ++h) {
            ushort8v w;
            if (isbf) w = AH[h];
            else {
                w[0] = f2bf(AF[h][0].x); w[1] = f2bf(AF[h][0].y);
                w[2] = f2bf(AF[h][0].z); w[3] = f2bf(AF[h][0].w);
                w[4] = f2bf(AF[h][1].x); w[5] = f2bf(AF[h][1].y);
                w[6] = f2bf(AF[h][1].z); w[7] = f2bf(AF[h][1].w);
            }
            *(ushort8v*)&Alds[buf][h][t * 8] = w;              // linear 16B granules
            *(ushort8v*)&Blds[buf][h][t * 8] = BR[h][0];
            *(ushort8v*)&Blds[buf][h][2048 + t * 8] = BR[h][1];
        }
    };
    auto compute = [&](int buf) {
#pragma unroll
        for (int h = 0; h < NH; ++h) {
            bf16x8 af[2], bfr[4];
#pragma unroll
            for (int i = 0; i < 2; ++i) {
                int m = wm * 32 + i * 16 + l15;
                af[i] = *(const bf16x8*)&Alds[buf][h][m * 32 + (q ^ ((m >> 2) & 3)) * 8];
            }
#pragma unroll
            for (int j = 0; j < 4; ++j) {
                int n = wn * 64 + j * 16 + l15;
                bfr[j] = *(const bf16x8*)&Blds[buf][h][n * 32 + (q ^ ((n >> 2) & 3)) * 8];
            }
#pragma unroll
            for (int i = 0; i < 2; ++i)
#pragma unroll
                for (int j = 0; j < 4; ++j)
                    acc[h][i][j] = MFMA(af[i], bfr[j], acc[h][i][j]);
        }
    };

    stage_load(0);
    stage_write(0);
    __syncthreads();
#pragma unroll 2
    for (int c = 0; c < 16; ++c) {
        if (c < 15) stage_load(c + 1);       // issue-early: overlap HBM/L3 with compute
        compute(c & 1);
        if (c < 15) {
            stage_write((c + 1) & 1);        // write-late into the other buffer
            __syncthreads();
        }
    }

    // epilogue: per-hop row scale d_h[i], hop-sum, plain stores to this ksplit's partial
    float* Pk = Pp + (size_t)kc * (Nn * Ddim);
#pragma unroll
    for (int i = 0; i < 2; ++i) {
#pragma unroll
        for (int r = 0; r < 4; ++r) {
            int row = wm * 32 + i * 16 + q * 4 + r;
            float d0 = dsh[0][row], d1 = dsh[1][row], d2 = dsh[2][row];
            float* pr = Pk + (size_t)(m0 + row) * Ddim + wn * 64 + l15;
#pragma unroll
            for (int j = 0; j < 4; ++j) {
                float v = d0 * acc[0][i][j][r] + d1 * acc[1][i][j][r] + d2 * acc[2][i][j][r];
                pr[j * 16] = v;
            }
        }
    }
}

// ---------------- K9: out = relu(sum_kc Pp[kc] + L), vectorized x4
__global__ void k9_combine(const float* __restrict__ Pp, const float* __restrict__ L,
                           void* __restrict__ outv, const float* __restrict__ mode) {
    bool isbf = mode[0] > 0.5f;
    size_t base = ((size_t)blockIdx.x * 256 + threadIdx.x) * 4;
    float4 a = *(const float4*)(L + base);
    float r0 = a.x, r1 = a.y, r2 = a.z, r3 = a.w;
#pragma unroll
    for (int kc = 0; kc < 8; ++kc) {
        float4 v = *(const float4*)(Pp + (size_t)kc * (Nn * Ddim) + base);
        r0 += v.x; r1 += v.y; r2 += v.z; r3 += v.w;
    }
    r0 = r0 > 0.f ? r0 : 0.f;
    r1 = r1 > 0.f ? r1 : 0.f;
    r2 = r2 > 0.f ? r2 : 0.f;
    r3 = r3 > 0.f ? r3 : 0.f;
    if (isbf) {
        ushort4v w;
        w[0] = f2bf(r0); w[1] = f2bf(r1); w[2] = f2bf(r2); w[3] = f2bf(r3);
        *(ushort4v*)((unsigned short*)outv + base) = w;
    } else {
        float4 w; w.x = r0; w.y = r1; w.z = r2; w.w = r3;
        *(float4*)((float*)outv + base) = w;
    }
}

extern "C" void kernel_launch(void* const* d_in, const int* in_sizes, int n_in,
                              void* d_out, int out_size, void* d_ws, size_t ws_size,
                              hipStream_t stream) {
    const void* X = d_in[0];
    const void* adj = d_in[1];
    const void* W_emb = d_in[2];
    const void* kernels = d_in[3];
    const void* alphap = d_in[4];

    // workspace layout (~34 MB)
    float* E = (float*)d_ws;            // 524288 f32
    float* XK = E + 524288;             // 1572864 f32
    float* rowsum = XK + 1572864;       // 12288 f32
    float* s = rowsum + 12288;          // 128 f32
    float* dbuf = s + 128;              // 12288 f32
    float* Mpart = dbuf + 12288;        // 393216 f32
    float* L = Mpart + 393216;          // 524288 f32
    float* Pp = L + 524288;             // 8 x 524288 f32 (K-split partials)
    unsigned short* WT = (unsigned short*)(Pp + 8 * 524288);  // 131072 u16
    unsigned short* ET = WT + 131072;   // 524288 u16
    unsigned short* Yp = ET + 524288;   // 1572864 u16  (Y^T row-major [h][128][4096])
    unsigned short* MT = Yp + 1572864;  // 49152 u16
    float* modef = (float*)(MT + 49152);// 1 f32

    // Order: all X-side work BEFORE the adj sweep, so that between k2 (which pulls
    // 201 MB f32 adj through L3) and k7 (which re-reads it) only ~15 MB of small
    // tensors intervene -> maximize k7's L3 hit rate on adj.
    kprobe<<<1, 64, 0, stream>>>((const unsigned short*)X, modef, s);
    k0_wt<<<8, 256, 0, stream>>>(W_emb, kernels, WT, modef);
    k1_proj<<<1024, 256, 0, stream>>>(X, WT, E, XK, s, modef);  // + fused colsum
    k2_rowsum<<<3072, 256, 0, stream>>>(adj, rowsum, modef);
    k4_dgen<<<128, 256, 0, stream>>>(E, rowsum, s, alphap, dbuf, modef);
    k5_transpose<<<256, 256, 0, stream>>>(XK, E, dbuf, Yp, ET);
    k6_mgen<<<192, 256, 0, stream>>>(ET, Yp, Mpart);
    k6b_mred<<<192, 256, 0, stream>>>(Mpart, MT);
    k8_lgen<<<256, 256, 0, stream>>>(E, dbuf, alphap, MT, L, modef);
    k7_fused<<<512, 256, 0, stream>>>(adj, Yp, dbuf, Pp, modef);
    k9_combine<<<512, 256, 0, stream>>>(Pp, L, d_out, modef);
}

// Round 7
// 377.396 us; speedup vs baseline: 1.3380x; 1.0183x over previous
//
#include <hip/hip_runtime.h>
#include <hip/hip_bf16.h>

#define Nn 4096
#define Fdim 256
#define Ddim 128
#define NH 3

typedef __bf16 bf16x8 __attribute__((ext_vector_type(8)));
typedef float f32x4 __attribute__((ext_vector_type(4)));
typedef unsigned short ushort8v __attribute__((ext_vector_type(8)));
typedef unsigned short ushort4v __attribute__((ext_vector_type(4)));

#define MFMA(a, b, c) __builtin_amdgcn_mfma_f32_16x16x32_bf16((a), (b), (c), 0, 0, 0)

__device__ __forceinline__ float bf2f(unsigned short u) {
    union { unsigned int i; float f; } cv;
    cv.i = ((unsigned int)u) << 16;
    return cv.f;
}
__device__ __forceinline__ unsigned short f2bf(float f) {
    union { __bf16 b; unsigned short u; } cv;
    cv.b = (__bf16)f;
    return cv.u;
}
__device__ __forceinline__ bf16x8 cvt8(const float* p, float s) {
    const float4 lo = *(const float4*)p;
    const float4 hi = *(const float4*)(p + 4);
    bf16x8 r;
    r[0] = (__bf16)(lo.x * s); r[1] = (__bf16)(lo.y * s);
    r[2] = (__bf16)(lo.z * s); r[3] = (__bf16)(lo.w * s);
    r[4] = (__bf16)(hi.x * s); r[5] = (__bf16)(hi.y * s);
    r[6] = (__bf16)(hi.z * s); r[7] = (__bf16)(hi.w * s);
    return r;
}

// ---------------- KP: dtype probe (bf16 vs f32 inputs); also zero-inits s[128].
__global__ void kprobe(const unsigned short* __restrict__ X, float* __restrict__ mode,
                       float* __restrict__ s) {
    int t = threadIdx.x;  // 64 threads, 1 block
    s[t] = 0.f;
    s[t + 64] = 0.f;
    int wild = 0;
    for (int i = t; i < 2048; i += 64) {
        unsigned short u = X[i];
        int e = (u >> 7) & 0xFF;
        if (e >= 132) wild = 1;
    }
    unsigned long long m = __ballot(wild != 0);
    if (t == 0) mode[0] = (__popcll(m) > 4) ? 0.0f : 1.0f;  // 1.0 => inputs are bf16
}

// ---------------- K0: W/kernels ([4][256][128] -> WT [4][128][256] bf16)
__global__ void k0_wt(const void* __restrict__ W_emb, const void* __restrict__ kernels,
                      unsigned short* __restrict__ WT, const float* __restrict__ mode) {
    bool isbf = mode[0] > 0.5f;
    int b = blockIdx.x, nt = b >> 1, fh = b & 1;
    __shared__ unsigned short T[128][136];
    int t = threadIdx.x;
    int d4 = t & 31, fr = t >> 5;
    if (isbf) {
        const unsigned short* Wsrc = (nt == 0) ? (const unsigned short*)W_emb
                                               : ((const unsigned short*)kernels + (size_t)(nt - 1) * Fdim * Ddim);
        for (int p = 0; p < 16; ++p) {
            int fl = fr + 8 * p;
            int f = fh * 128 + fl;
            ushort4v v = *(const ushort4v*)(Wsrc + (size_t)f * Ddim + 4 * d4);
            T[4 * d4 + 0][fl] = v[0]; T[4 * d4 + 1][fl] = v[1];
            T[4 * d4 + 2][fl] = v[2]; T[4 * d4 + 3][fl] = v[3];
        }
    } else {
        const float* Wsrc = (nt == 0) ? (const float*)W_emb
                                      : ((const float*)kernels + (size_t)(nt - 1) * Fdim * Ddim);
        for (int p = 0; p < 16; ++p) {
            int fl = fr + 8 * p;
            int f = fh * 128 + fl;
            float4 v = *(const float4*)(Wsrc + (size_t)f * Ddim + 4 * d4);
            T[4 * d4 + 0][fl] = f2bf(v.x); T[4 * d4 + 1][fl] = f2bf(v.y);
            T[4 * d4 + 2][fl] = f2bf(v.z); T[4 * d4 + 3][fl] = f2bf(v.w);
        }
    }
    __syncthreads();
    int f4 = t & 31, dr = t >> 5;
    for (int p = 0; p < 16; ++p) {
        int dd = dr + 8 * p;
        ushort4v w;
        w[0] = T[dd][4 * f4 + 0]; w[1] = T[dd][4 * f4 + 1];
        w[2] = T[dd][4 * f4 + 2]; w[3] = T[dd][4 * f4 + 3];
        *(ushort4v*)(WT + (size_t)nt * Ddim * Fdim + (size_t)dd * Fdim + fh * 128 + 4 * f4) = w;
    }
}

// ---------------- K12: merged projection + adj rowsum (independent work, one dispatch).
// Blocks 0..1023: [E | XK0 | XK1 | XK2] = X @ [W_emb | k0..k2]; nt==0 blocks also
// accumulate E column-sums into s. Blocks 1024..4095: adj rowsums, one wave per row.
// MFMA-bound proj waves and BW-bound rowsum waves co-schedule on the device (m114);
// the adj sweep also leaves L3 warm with adj right before k7's re-read.
__global__ void k12_proj_rowsum(const void* __restrict__ Xv, const unsigned short* __restrict__ WT,
                                float* __restrict__ E, float* __restrict__ XK, float* __restrict__ s,
                                const void* __restrict__ adjv, float* __restrict__ rowsum,
                                const float* __restrict__ mode) {
    bool isbf = mode[0] > 0.5f;
    int b = blockIdx.x;
    int t = threadIdx.x;
    if (b < 1024) {
        // ---- projection part (old k1)
        int mt = b >> 2, nt = b & 3;
        int wid = t >> 6, lane = t & 63, l15 = lane & 15, q = lane >> 4;
        int m0 = mt * 16;
        const unsigned short* BT = WT + (size_t)nt * Ddim * Fdim;
        const unsigned short* b0p = BT + (size_t)(wid * 32 + l15) * Fdim;
        const unsigned short* b1p = b0p + 16 * Fdim;
        f32x4 acc0 = {0.f, 0.f, 0.f, 0.f}, acc1 = {0.f, 0.f, 0.f, 0.f};
        if (isbf) {
            const unsigned short* Arow = (const unsigned short*)Xv + (size_t)(m0 + l15) * Fdim;
#pragma unroll
            for (int ks = 0; ks < 8; ++ks) {
                int kk = ks * 32 + q * 8;
                bf16x8 a = *(const bf16x8*)(Arow + kk);
                bf16x8 b0 = *(const bf16x8*)(b0p + kk);
                bf16x8 b1 = *(const bf16x8*)(b1p + kk);
                acc0 = MFMA(a, b0, acc0);
                acc1 = MFMA(a, b1, acc1);
            }
        } else {
            const float* Arow = (const float*)Xv + (size_t)(m0 + l15) * Fdim;
#pragma unroll
            for (int ks = 0; ks < 8; ++ks) {
                int kk = ks * 32 + q * 8;
                bf16x8 a = cvt8(Arow + kk, 1.0f);
                bf16x8 b0 = *(const bf16x8*)(b0p + kk);
                bf16x8 b1 = *(const bf16x8*)(b1p + kk);
                acc0 = MFMA(a, b0, acc0);
                acc1 = MFMA(a, b1, acc1);
            }
        }
        float* dst = (nt == 0) ? E : (XK + (size_t)(nt - 1) * Nn * Ddim);
#pragma unroll
        for (int r = 0; r < 4; ++r) {
            int ml = q * 4 + r;
            dst[(size_t)(m0 + ml) * Ddim + wid * 32 + l15] = acc0[r];
            dst[(size_t)(m0 + ml) * Ddim + wid * 32 + 16 + l15] = acc1[r];
        }
        if (nt == 0) {
            float c0 = acc0[0] + acc0[1] + acc0[2] + acc0[3];
            float c1 = acc1[0] + acc1[1] + acc1[2] + acc1[3];
            c0 += __shfl_xor(c0, 16, 64); c0 += __shfl_xor(c0, 32, 64);
            c1 += __shfl_xor(c1, 16, 64); c1 += __shfl_xor(c1, 32, 64);
            if (q == 0) {
                atomicAdd(&s[wid * 32 + l15], c0);
                atomicAdd(&s[wid * 32 + 16 + l15], c1);
            }
        }
    } else {
        // ---- rowsum part (old k2): one wave per adj row
        int w = t >> 6, lane = t & 63;
        int r = (b - 1024) * 4 + w;
        float sum = 0.f;
        if (isbf) {
            const unsigned short* rp = (const unsigned short*)adjv + (size_t)r * Nn;
#pragma unroll
            for (int it = 0; it < 8; ++it) {
                ushort8v v = *(const ushort8v*)(rp + (it * 64 + lane) * 8);
                sum += bf2f(v[0]) + bf2f(v[1]) + bf2f(v[2]) + bf2f(v[3]) +
                       bf2f(v[4]) + bf2f(v[5]) + bf2f(v[6]) + bf2f(v[7]);
            }
        } else {
            const float4* rp = (const float4*)((const float*)adjv + (size_t)r * Nn);
#pragma unroll
            for (int it = 0; it < 16; ++it) {
                float4 v = rp[it * 64 + lane];
                sum += v.x + v.y + v.z + v.w;
            }
        }
#pragma unroll
        for (int off = 32; off > 0; off >>= 1) sum += __shfl_down(sum, off, 64);
        if (lane == 0) rowsum[r] = sum;
    }
}

// ---------------- K5: build Y^T[h][n][j] = bf16(d_h[j]*XK[h][j][n]) row-major [128][4096]
// and row-major ET[d][j] = bf16(E[j][d]). 256 blocks (192 Y tiles + 64 ET tiles of 64 nodes).
// Y blocks also GENERATE d for their 64 nodes (d = rsqrt(rowsum + alpha*dot(E,s)))
// and write it to dbuf — replaces the old k4_dgen kernel.
__global__ void k5_transpose(const float* __restrict__ XK, const float* __restrict__ E,
                             const float* __restrict__ rowsum, const float* __restrict__ s,
                             const void* __restrict__ alphap, float* __restrict__ dbuf,
                             unsigned short* __restrict__ Yp, unsigned short* __restrict__ ET,
                             const float* __restrict__ mode) {
    bool isbf = mode[0] > 0.5f;
    __shared__ unsigned short T[128][72];
    __shared__ float sl[64];
    __shared__ float ss[128];
    int b = blockIdx.x, t = threadIdx.x;
    bool isET = (b >= 192);
    int h = 0, jt;
    const float* src;
    if (!isET) { h = b >> 6; jt = b & 63; src = XK + (size_t)h * Nn * Ddim; }
    else { jt = b - 192; src = E; }
    if (isET) {
        if (t < 64) sl[t] = 1.0f;
    } else {
        if (t < 128) ss[t] = s[t];
        __syncthreads();
        // d-gen: node = t>>2 (0..63), quarter sub = t&3 over 32 columns each
        int node = t >> 2, sub = t & 3;
        int gn = jt * 64 + node;
        const float4* er = (const float4*)(E + (size_t)gn * Ddim + sub * 32);
        float acc = 0.f;
#pragma unroll
        for (int k = 0; k < 8; ++k) {
            float4 v = er[k];
            int c = sub * 32 + 4 * k;
            acc += v.x * ss[c] + v.y * ss[c + 1] + v.z * ss[c + 2] + v.w * ss[c + 3];
        }
        acc += __shfl_xor(acc, 1, 64);
        acc += __shfl_xor(acc, 2, 64);
        if (sub == 0) {
            float a = isbf ? bf2f(((const unsigned short*)alphap)[0]) : ((const float*)alphap)[0];
            float d = rsqrtf(rowsum[h * Nn + gn] + a * acc);
            sl[node] = d;
            dbuf[h * Nn + gn] = d;
        }
    }
    __syncthreads();
    int d4 = t & 31, jr = t >> 5;
    for (int p = 0; p < 8; ++p) {
        int j = jr + 8 * p;  // 0..63
        float4 v = *(const float4*)(src + (size_t)(jt * 64 + j) * Ddim + 4 * d4);
        float sc = sl[j];
        T[4 * d4 + 0][j] = f2bf(v.x * sc); T[4 * d4 + 1][j] = f2bf(v.y * sc);
        T[4 * d4 + 2][j] = f2bf(v.z * sc); T[4 * d4 + 3][j] = f2bf(v.w * sc);
    }
    __syncthreads();
    int jj4 = t & 15, nr = t >> 4;
    unsigned short* dst = isET ? ET : (Yp + (size_t)h * Ddim * Nn);
    for (int p = 0; p < 8; ++p) {
        int n = nr + 16 * p;  // 0..127
        ushort4v w;
        w[0] = T[n][4 * jj4 + 0]; w[1] = T[n][4 * jj4 + 1];
        w[2] = T[n][4 * jj4 + 2]; w[3] = T[n][4 * jj4 + 3];
        int j = jt * 64 + 4 * jj4;
        *(ushort4v*)(dst + (size_t)n * Nn + j) = w;
    }
}

// ---------------- K6: Mpart[kc][h] = (E^T @ Y_h) partial over K-chunk (Y^T row-major)
__global__ void k6_mgen(const unsigned short* __restrict__ ET,
                        const unsigned short* __restrict__ Yp, float* __restrict__ Mpart) {
    int b = blockIdx.x;
    int kc = b / 24, rem = b % 24, h = rem >> 3, mtm = rem & 7;
    int t = threadIdx.x, wid = t >> 6, lane = t & 63, l15 = lane & 15, q = lane >> 4;
    int m0 = mtm * 16;
    const unsigned short* Ar = ET + (size_t)(m0 + l15) * Nn + kc * 512;
    const unsigned short* Yph = Yp + (size_t)h * Ddim * Nn;
    const unsigned short* bb = Yph + (size_t)(wid * 32 + l15) * Nn + kc * 512 + q * 8;
    f32x4 acc0 = {0.f, 0.f, 0.f, 0.f}, acc1 = {0.f, 0.f, 0.f, 0.f};
#pragma unroll 4
    for (int ks = 0; ks < 16; ++ks) {
        bf16x8 a = *(const bf16x8*)(Ar + ks * 32 + q * 8);
        bf16x8 b0 = *(const bf16x8*)(bb + ks * 32);
        bf16x8 b1 = *(const bf16x8*)(bb + (size_t)16 * Nn + ks * 32);
        acc0 = MFMA(a, b0, acc0);
        acc1 = MFMA(a, b1, acc1);
    }
    float* out = Mpart + (size_t)kc * (NH * Ddim * Ddim) + (size_t)h * (Ddim * Ddim);
#pragma unroll
    for (int r = 0; r < 4; ++r) {
        int ml = q * 4 + r;
        out[(m0 + ml) * Ddim + wid * 32 + l15] = acc0[r];
        out[(m0 + ml) * Ddim + wid * 32 + 16 + l15] = acc1[r];
    }
}

// ---------------- K6b: reduce 8 K-chunks and transpose: MT[d2][h*128+d1] bf16
__global__ void k6b_mred(const float* __restrict__ Mpart, unsigned short* __restrict__ MT) {
    int idx = blockIdx.x * 256 + threadIdx.x;  // < 49152
    int d2 = idx / 384, kcol = idx % 384;
    int h = kcol >> 7, d1 = kcol & 127;
    float sum = 0.f;
#pragma unroll
    for (int kc = 0; kc < 8; ++kc)
        sum += Mpart[(size_t)kc * (NH * Ddim * Ddim) + h * (Ddim * Ddim) + d1 * Ddim + d2];
    MT[idx] = f2bf(sum);
}

// ---------------- K8: L = sum_h alpha*d_h[i] * (E @ M_h), MFMA over K=384
__global__ void k8_lgen(const float* __restrict__ E, const float* __restrict__ dbuf,
                        const void* __restrict__ alphap, const unsigned short* __restrict__ MT,
                        float* __restrict__ L, const float* __restrict__ mode) {
    bool isbf = mode[0] > 0.5f;
    int mt = blockIdx.x;
    int t = threadIdx.x, wid = t >> 6, lane = t & 63, l15 = lane & 15, q = lane >> 4;
    int m0 = mt * 16, m = m0 + l15;
    float a = isbf ? bf2f(((const unsigned short*)alphap)[0]) : ((const float*)alphap)[0];
    float dv[NH];
#pragma unroll
    for (int h = 0; h < NH; ++h) dv[h] = a * dbuf[h * Nn + m];
    const float* Er = E + (size_t)m * Ddim;
    const unsigned short* b0p = MT + (size_t)(wid * 32 + l15) * 384;
    const unsigned short* b1p = b0p + 16 * 384;
    f32x4 acc0 = {0.f, 0.f, 0.f, 0.f}, acc1 = {0.f, 0.f, 0.f, 0.f};
#pragma unroll
    for (int ks = 0; ks < 12; ++ks) {
        int kk = ks * 32;
        int h = kk >> 7;
        int kloc = (kk & 127) + q * 8;
        bf16x8 aa = cvt8(Er + kloc, dv[h]);
        bf16x8 b0 = *(const bf16x8*)(b0p + kk + q * 8);
        bf16x8 b1 = *(const bf16x8*)(b1p + kk + q * 8);
        acc0 = MFMA(aa, b0, acc0);
        acc1 = MFMA(aa, b1, acc1);
    }
#pragma unroll
    for (int r = 0; r < 4; ++r) {
        int ml = q * 4 + r;
        L[(size_t)(m0 + ml) * Ddim + wid * 32 + l15] = acc0[r];
        L[(size_t)(m0 + ml) * Ddim + wid * 32 + 16 + l15] = acc1[r];
    }
}

// ---------------- K7: hop-merged, K-split main GEMM — unchanged from R6 (measured-good).
// Grid = 64 mtiles (64 rows) x 8 ksplits = 512 blocks x 256 threads, LDS 72 KB
// -> 2 blocks/CU for cross-block latency overlap at the barrier drain.
__global__ void __launch_bounds__(256, 2) k7_fused(const void* __restrict__ adjv,
        const unsigned short* __restrict__ Yp, const float* __restrict__ dbuf,
        float* __restrict__ Pp, const float* __restrict__ mode) {
    bool isbf = mode[0] > 0.5f;
    __shared__ unsigned short Alds[2][NH][64 * 32];   // 24 KB
    __shared__ unsigned short Blds[2][NH][128 * 32];  // 48 KB
    __shared__ float dsh[NH][64];
    int b = blockIdx.x;
    int mt = b >> 3, kc = b & 7;
    int m0 = mt * 64;
    int kbase = kc * 512;
    int t = threadIdx.x;
    if (t < 192) { int h = t >> 6, m = t & 63; dsh[h][m] = dbuf[h * Nn + m0 + m]; }

    int sr = t >> 2, ss = t & 3;
    int sw = ss ^ ((sr >> 2) & 3);
    const float* aBaseF = (const float*)adjv + (size_t)(m0 + sr) * Nn + kbase + 8 * sw;
    const unsigned short* aBaseH = (const unsigned short*)adjv + (size_t)(m0 + sr) * Nn + kbase + 8 * sw;
    const unsigned short* bBase = Yp + (size_t)sr * Nn + kbase + 8 * sw;

    int wid = t >> 6, lane = t & 63, l15 = lane & 15, q = lane >> 4;
    int wm = wid >> 1, wn = wid & 1;
    f32x4 acc[NH][2][4] = {};

    float4 AF[NH][2];
    ushort8v AH[NH];
    ushort8v BR[NH][2];

    auto stage_load = [&](int c) {
        int ko = c * 32;
        if (isbf) {
#pragma unroll
            for (int h = 0; h < NH; ++h)
                AH[h] = *(const ushort8v*)(aBaseH + (size_t)h * Nn * Nn + ko);
        } else {
#pragma unroll
            for (int h = 0; h < NH; ++h) {
                AF[h][0] = *(const float4*)(aBaseF + (size_t)h * Nn * Nn + ko);
                AF[h][1] = *(const float4*)(aBaseF + (size_t)h * Nn * Nn + ko + 4);
            }
        }
#pragma unroll
        for (int h = 0; h < NH; ++h) {
            BR[h][0] = *(const ushort8v*)(bBase + (size_t)h * Ddim * Nn + ko);
            BR[h][1] = *(const ushort8v*)(bBase + (size_t)h * Ddim * Nn + (size_t)64 * Nn + ko);
        }
    };
    auto stage_write = [&](int buf) {
#pragma unroll
        for (int h = 0; h < NH; ++h) {
            ushort8v w;
            if (isbf) w = AH[h];
            else {
                w[0] = f2bf(AF[h][0].x); w[1] = f2bf(AF[h][0].y);
                w[2] = f2bf(AF[h][0].z); w[3] = f2bf(AF[h][0].w);
                w[4] = f2bf(AF[h][1].x); w[5] = f2bf(AF[h][1].y);
                w[6] = f2bf(AF[h][1].z); w[7] = f2bf(AF[h][1].w);
            }
            *(ushort8v*)&Alds[buf][h][t * 8] = w;
            *(ushort8v*)&Blds[buf][h][t * 8] = BR[h][0];
            *(ushort8v*)&Blds[buf][h][2048 + t * 8] = BR[h][1];
        }
    };
    auto compute = [&](int buf) {
#pragma unroll
        for (int h = 0; h < NH; ++h) {
            bf16x8 af[2], bfr[4];
#pragma unroll
            for (int i = 0; i < 2; ++i) {
                int m = wm * 32 + i * 16 + l15;
                af[i] = *(const bf16x8*)&Alds[buf][h][m * 32 + (q ^ ((m >> 2) & 3)) * 8];
            }
#pragma unroll
            for (int j = 0; j < 4; ++j) {
                int n = wn * 64 + j * 16 + l15;
                bfr[j] = *(const bf16x8*)&Blds[buf][h][n * 32 + (q ^ ((n >> 2) & 3)) * 8];
            }
#pragma unroll
            for (int i = 0; i < 2; ++i)
#pragma unroll
                for (int j = 0; j < 4; ++j)
                    acc[h][i][j] = MFMA(af[i], bfr[j], acc[h][i][j]);
        }
    };

    stage_load(0);
    stage_write(0);
    __syncthreads();
#pragma unroll 2
    for (int c = 0; c < 16; ++c) {
        if (c < 15) stage_load(c + 1);
        compute(c & 1);
        if (c < 15) {
            stage_write((c + 1) & 1);
            __syncthreads();
        }
    }

    float* Pk = Pp + (size_t)kc * (Nn * Ddim);
#pragma unroll
    for (int i = 0; i < 2; ++i) {
#pragma unroll
        for (int r = 0; r < 4; ++r) {
            int row = wm * 32 + i * 16 + q * 4 + r;
            float d0 = dsh[0][row], d1 = dsh[1][row], d2 = dsh[2][row];
            float* pr = Pk + (size_t)(m0 + row) * Ddim + wn * 64 + l15;
#pragma unroll
            for (int j = 0; j < 4; ++j) {
                float v = d0 * acc[0][i][j][r] + d1 * acc[1][i][j][r] + d2 * acc[2][i][j][r];
                pr[j * 16] = v;
            }
        }
    }
}

// ---------------- K9: out = relu(sum_kc Pp[kc] + L), vectorized x4
__global__ void k9_combine(const float* __restrict__ Pp, const float* __restrict__ L,
                           void* __restrict__ outv, const float* __restrict__ mode) {
    bool isbf = mode[0] > 0.5f;
    size_t base = ((size_t)blockIdx.x * 256 + threadIdx.x) * 4;
    float4 a = *(const float4*)(L + base);
    float r0 = a.x, r1 = a.y, r2 = a.z, r3 = a.w;
#pragma unroll
    for (int kc = 0; kc < 8; ++kc) {
        float4 v = *(const float4*)(Pp + (size_t)kc * (Nn * Ddim) + base);
        r0 += v.x; r1 += v.y; r2 += v.z; r3 += v.w;
    }
    r0 = r0 > 0.f ? r0 : 0.f;
    r1 = r1 > 0.f ? r1 : 0.f;
    r2 = r2 > 0.f ? r2 : 0.f;
    r3 = r3 > 0.f ? r3 : 0.f;
    if (isbf) {
        ushort4v w;
        w[0] = f2bf(r0); w[1] = f2bf(r1); w[2] = f2bf(r2); w[3] = f2bf(r3);
        *(ushort4v*)((unsigned short*)outv + base) = w;
    } else {
        float4 w; w.x = r0; w.y = r1; w.z = r2; w.w = r3;
        *(float4*)((float*)outv + base) = w;
    }
}

extern "C" void kernel_launch(void* const* d_in, const int* in_sizes, int n_in,
                              void* d_out, int out_size, void* d_ws, size_t ws_size,
                              hipStream_t stream) {
    const void* X = d_in[0];
    const void* adj = d_in[1];
    const void* W_emb = d_in[2];
    const void* kernels = d_in[3];
    const void* alphap = d_in[4];

    // workspace layout (~34 MB)
    float* E = (float*)d_ws;            // 524288 f32
    float* XK = E + 524288;             // 1572864 f32
    float* rowsum = XK + 1572864;       // 12288 f32
    float* s = rowsum + 12288;          // 128 f32
    float* dbuf = s + 128;              // 12288 f32
    float* Mpart = dbuf + 12288;        // 393216 f32
    float* L = Mpart + 393216;          // 524288 f32
    float* Pp = L + 524288;             // 8 x 524288 f32 (K-split partials)
    unsigned short* WT = (unsigned short*)(Pp + 8 * 524288);  // 131072 u16
    unsigned short* ET = WT + 131072;   // 524288 u16
    unsigned short* Yp = ET + 524288;   // 1572864 u16  (Y^T row-major [h][128][4096])
    unsigned short* MT = Yp + 1572864;  // 49152 u16
    float* modef = (float*)(MT + 49152);// 1 f32

    kprobe<<<1, 64, 0, stream>>>((const unsigned short*)X, modef, s);
    k0_wt<<<8, 256, 0, stream>>>(W_emb, kernels, WT, modef);
    // merged proj+rowsum: MFMA and BW waves co-resident; leaves L3 warm with adj
    k12_proj_rowsum<<<4096, 256, 0, stream>>>(X, WT, E, XK, s, adj, rowsum, modef);
    k5_transpose<<<256, 256, 0, stream>>>(XK, E, rowsum, s, alphap, dbuf, Yp, ET, modef);  // + d-gen
    k6_mgen<<<192, 256, 0, stream>>>(ET, Yp, Mpart);
    k6b_mred<<<192, 256, 0, stream>>>(Mpart, MT);
    k8_lgen<<<256, 256, 0, stream>>>(E, dbuf, alphap, MT, L, modef);
    k7_fused<<<512, 256, 0, stream>>>(adj, Yp, dbuf, Pp, modef);
    k9_combine<<<512, 256, 0, stream>>>(Pp, L, d_out, modef);
}

// Round 8
// 364.748 us; speedup vs baseline: 1.3844x; 1.0347x over previous
//
#include <hip/hip_runtime.h>
#include <hip/hip_bf16.h>

#define Nn 4096
#define Fdim 256
#define Ddim 128
#define NH 3

typedef __bf16 bf16x8 __attribute__((ext_vector_type(8)));
typedef float f32x4 __attribute__((ext_vector_type(4)));
typedef unsigned short ushort8v __attribute__((ext_vector_type(8)));
typedef unsigned short ushort4v __attribute__((ext_vector_type(4)));

#define MFMA(a, b, c) __builtin_amdgcn_mfma_f32_16x16x32_bf16((a), (b), (c), 0, 0, 0)

__device__ __forceinline__ float bf2f(unsigned short u) {
    union { unsigned int i; float f; } cv;
    cv.i = ((unsigned int)u) << 16;
    return cv.f;
}
__device__ __forceinline__ unsigned short f2bf(float f) {
    union { __bf16 b; unsigned short u; } cv;
    cv.b = (__bf16)f;
    return cv.u;
}
__device__ __forceinline__ bf16x8 cvt8(const float* p, float s) {
    const float4 lo = *(const float4*)p;
    const float4 hi = *(const float4*)(p + 4);
    bf16x8 r;
    r[0] = (__bf16)(lo.x * s); r[1] = (__bf16)(lo.y * s);
    r[2] = (__bf16)(lo.z * s); r[3] = (__bf16)(lo.w * s);
    r[4] = (__bf16)(hi.x * s); r[5] = (__bf16)(hi.y * s);
    r[6] = (__bf16)(hi.z * s); r[7] = (__bf16)(hi.w * s);
    return r;
}

// ---------------- K0: W/kernels ([4][256][128] -> WT [4][128][256] bf16).
// Self-probes dtype (identical 64-thread probe as the old kprobe, wave-0 ballot);
// block 0 publishes mode[0] and zero-inits s[128]. Replaces the kprobe launch.
__global__ void k0_wt(const void* __restrict__ W_emb, const void* __restrict__ kernels,
                      unsigned short* __restrict__ WT, const unsigned short* __restrict__ X,
                      float* __restrict__ mode, float* __restrict__ s) {
    __shared__ float smode;
    int b = blockIdx.x, t = threadIdx.x;
    if (t < 64) {
        int wild = 0;
        for (int i = t; i < 2048; i += 64) {
            unsigned short u = X[i];
            int e = (u >> 7) & 0xFF;
            if (e >= 132) wild = 1;
        }
        unsigned long long mba = __ballot(wild != 0);  // wave 0 fully active
        if (t == 0) smode = (__popcll(mba) > 4) ? 0.0f : 1.0f;  // 1.0 => bf16 inputs
    }
    __syncthreads();
    bool isbf = smode > 0.5f;
    if (b == 0 && t < 128) {
        s[t] = 0.f;
        if (t == 0) mode[0] = smode;
    }
    int nt = b >> 1, fh = b & 1;
    __shared__ unsigned short T[128][136];
    int d4 = t & 31, fr = t >> 5;
    if (isbf) {
        const unsigned short* Wsrc = (nt == 0) ? (const unsigned short*)W_emb
                                               : ((const unsigned short*)kernels + (size_t)(nt - 1) * Fdim * Ddim);
        for (int p = 0; p < 16; ++p) {
            int fl = fr + 8 * p;
            int f = fh * 128 + fl;
            ushort4v v = *(const ushort4v*)(Wsrc + (size_t)f * Ddim + 4 * d4);
            T[4 * d4 + 0][fl] = v[0]; T[4 * d4 + 1][fl] = v[1];
            T[4 * d4 + 2][fl] = v[2]; T[4 * d4 + 3][fl] = v[3];
        }
    } else {
        const float* Wsrc = (nt == 0) ? (const float*)W_emb
                                      : ((const float*)kernels + (size_t)(nt - 1) * Fdim * Ddim);
        for (int p = 0; p < 16; ++p) {
            int fl = fr + 8 * p;
            int f = fh * 128 + fl;
            float4 v = *(const float4*)(Wsrc + (size_t)f * Ddim + 4 * d4);
            T[4 * d4 + 0][fl] = f2bf(v.x); T[4 * d4 + 1][fl] = f2bf(v.y);
            T[4 * d4 + 2][fl] = f2bf(v.z); T[4 * d4 + 3][fl] = f2bf(v.w);
        }
    }
    __syncthreads();
    int f4 = t & 31, dr = t >> 5;
    for (int p = 0; p < 16; ++p) {
        int dd = dr + 8 * p;
        ushort4v w;
        w[0] = T[dd][4 * f4 + 0]; w[1] = T[dd][4 * f4 + 1];
        w[2] = T[dd][4 * f4 + 2]; w[3] = T[dd][4 * f4 + 3];
        *(ushort4v*)(WT + (size_t)nt * Ddim * Fdim + (size_t)dd * Fdim + fh * 128 + 4 * f4) = w;
    }
}

// ---------------- K12: merged projection + adj rowsum (independent work, one dispatch).
// Blocks 0..1023: [E | XK0 | XK1 | XK2] = X @ [W_emb | k0..k2]; nt==0 blocks also
// accumulate E column-sums into s. Blocks 1024..4095: adj rowsums, one wave per row.
__global__ void k12_proj_rowsum(const void* __restrict__ Xv, const unsigned short* __restrict__ WT,
                                float* __restrict__ E, float* __restrict__ XK, float* __restrict__ s,
                                const void* __restrict__ adjv, float* __restrict__ rowsum,
                                const float* __restrict__ mode) {
    bool isbf = mode[0] > 0.5f;
    int b = blockIdx.x;
    int t = threadIdx.x;
    if (b < 1024) {
        int mt = b >> 2, nt = b & 3;
        int wid = t >> 6, lane = t & 63, l15 = lane & 15, q = lane >> 4;
        int m0 = mt * 16;
        const unsigned short* BT = WT + (size_t)nt * Ddim * Fdim;
        const unsigned short* b0p = BT + (size_t)(wid * 32 + l15) * Fdim;
        const unsigned short* b1p = b0p + 16 * Fdim;
        f32x4 acc0 = {0.f, 0.f, 0.f, 0.f}, acc1 = {0.f, 0.f, 0.f, 0.f};
        if (isbf) {
            const unsigned short* Arow = (const unsigned short*)Xv + (size_t)(m0 + l15) * Fdim;
#pragma unroll
            for (int ks = 0; ks < 8; ++ks) {
                int kk = ks * 32 + q * 8;
                bf16x8 a = *(const bf16x8*)(Arow + kk);
                bf16x8 b0 = *(const bf16x8*)(b0p + kk);
                bf16x8 b1 = *(const bf16x8*)(b1p + kk);
                acc0 = MFMA(a, b0, acc0);
                acc1 = MFMA(a, b1, acc1);
            }
        } else {
            const float* Arow = (const float*)Xv + (size_t)(m0 + l15) * Fdim;
#pragma unroll
            for (int ks = 0; ks < 8; ++ks) {
                int kk = ks * 32 + q * 8;
                bf16x8 a = cvt8(Arow + kk, 1.0f);
                bf16x8 b0 = *(const bf16x8*)(b0p + kk);
                bf16x8 b1 = *(const bf16x8*)(b1p + kk);
                acc0 = MFMA(a, b0, acc0);
                acc1 = MFMA(a, b1, acc1);
            }
        }
        float* dst = (nt == 0) ? E : (XK + (size_t)(nt - 1) * Nn * Ddim);
#pragma unroll
        for (int r = 0; r < 4; ++r) {
            int ml = q * 4 + r;
            dst[(size_t)(m0 + ml) * Ddim + wid * 32 + l15] = acc0[r];
            dst[(size_t)(m0 + ml) * Ddim + wid * 32 + 16 + l15] = acc1[r];
        }
        if (nt == 0) {
            float c0 = acc0[0] + acc0[1] + acc0[2] + acc0[3];
            float c1 = acc1[0] + acc1[1] + acc1[2] + acc1[3];
            c0 += __shfl_xor(c0, 16, 64); c0 += __shfl_xor(c0, 32, 64);
            c1 += __shfl_xor(c1, 16, 64); c1 += __shfl_xor(c1, 32, 64);
            if (q == 0) {
                atomicAdd(&s[wid * 32 + l15], c0);
                atomicAdd(&s[wid * 32 + 16 + l15], c1);
            }
        }
    } else {
        int w = t >> 6, lane = t & 63;
        int r = (b - 1024) * 4 + w;
        float sum = 0.f;
        if (isbf) {
            const unsigned short* rp = (const unsigned short*)adjv + (size_t)r * Nn;
#pragma unroll
            for (int it = 0; it < 8; ++it) {
                ushort8v v = *(const ushort8v*)(rp + (it * 64 + lane) * 8);
                sum += bf2f(v[0]) + bf2f(v[1]) + bf2f(v[2]) + bf2f(v[3]) +
                       bf2f(v[4]) + bf2f(v[5]) + bf2f(v[6]) + bf2f(v[7]);
            }
        } else {
            const float4* rp = (const float4*)((const float*)adjv + (size_t)r * Nn);
#pragma unroll
            for (int it = 0; it < 16; ++it) {
                float4 v = rp[it * 64 + lane];
                sum += v.x + v.y + v.z + v.w;
            }
        }
#pragma unroll
        for (int off = 32; off > 0; off >>= 1) sum += __shfl_down(sum, off, 64);
        if (lane == 0) rowsum[r] = sum;
    }
}

// ---------------- K5: build Y^T[h][n][j] = bf16(d_h[j]*XK[h][j][n]) row-major [128][4096]
// and row-major ET[d][j] = bf16(E[j][d]). Y blocks also generate d (replaces k4).
__global__ void k5_transpose(const float* __restrict__ XK, const float* __restrict__ E,
                             const float* __restrict__ rowsum, const float* __restrict__ s,
                             const void* __restrict__ alphap, float* __restrict__ dbuf,
                             unsigned short* __restrict__ Yp, unsigned short* __restrict__ ET,
                             const float* __restrict__ mode) {
    bool isbf = mode[0] > 0.5f;
    __shared__ unsigned short T[128][72];
    __shared__ float sl[64];
    __shared__ float ss[128];
    int b = blockIdx.x, t = threadIdx.x;
    bool isET = (b >= 192);
    int h = 0, jt;
    const float* src;
    if (!isET) { h = b >> 6; jt = b & 63; src = XK + (size_t)h * Nn * Ddim; }
    else { jt = b - 192; src = E; }
    if (isET) {
        if (t < 64) sl[t] = 1.0f;
    } else {
        if (t < 128) ss[t] = s[t];
        __syncthreads();
        int node = t >> 2, sub = t & 3;
        int gn = jt * 64 + node;
        const float4* er = (const float4*)(E + (size_t)gn * Ddim + sub * 32);
        float acc = 0.f;
#pragma unroll
        for (int k = 0; k < 8; ++k) {
            float4 v = er[k];
            int c = sub * 32 + 4 * k;
            acc += v.x * ss[c] + v.y * ss[c + 1] + v.z * ss[c + 2] + v.w * ss[c + 3];
        }
        acc += __shfl_xor(acc, 1, 64);
        acc += __shfl_xor(acc, 2, 64);
        if (sub == 0) {
            float a = isbf ? bf2f(((const unsigned short*)alphap)[0]) : ((const float*)alphap)[0];
            float d = rsqrtf(rowsum[h * Nn + gn] + a * acc);
            sl[node] = d;
            dbuf[h * Nn + gn] = d;
        }
    }
    __syncthreads();
    int d4 = t & 31, jr = t >> 5;
    for (int p = 0; p < 8; ++p) {
        int j = jr + 8 * p;  // 0..63
        float4 v = *(const float4*)(src + (size_t)(jt * 64 + j) * Ddim + 4 * d4);
        float sc = sl[j];
        T[4 * d4 + 0][j] = f2bf(v.x * sc); T[4 * d4 + 1][j] = f2bf(v.y * sc);
        T[4 * d4 + 2][j] = f2bf(v.z * sc); T[4 * d4 + 3][j] = f2bf(v.w * sc);
    }
    __syncthreads();
    int jj4 = t & 15, nr = t >> 4;
    unsigned short* dst = isET ? ET : (Yp + (size_t)h * Ddim * Nn);
    for (int p = 0; p < 8; ++p) {
        int n = nr + 16 * p;  // 0..127
        ushort4v w;
        w[0] = T[n][4 * jj4 + 0]; w[1] = T[n][4 * jj4 + 1];
        w[2] = T[n][4 * jj4 + 2]; w[3] = T[n][4 * jj4 + 3];
        int j = jt * 64 + 4 * jj4;
        *(ushort4v*)(dst + (size_t)n * Nn + j) = w;
    }
}

// ---------------- K6: Mpart[kc][h] = (E^T @ Y_h) partial over K-chunk (Y^T row-major)
__global__ void k6_mgen(const unsigned short* __restrict__ ET,
                        const unsigned short* __restrict__ Yp, float* __restrict__ Mpart) {
    int b = blockIdx.x;
    int kc = b / 24, rem = b % 24, h = rem >> 3, mtm = rem & 7;
    int t = threadIdx.x, wid = t >> 6, lane = t & 63, l15 = lane & 15, q = lane >> 4;
    int m0 = mtm * 16;
    const unsigned short* Ar = ET + (size_t)(m0 + l15) * Nn + kc * 512;
    const unsigned short* Yph = Yp + (size_t)h * Ddim * Nn;
    const unsigned short* bb = Yph + (size_t)(wid * 32 + l15) * Nn + kc * 512 + q * 8;
    f32x4 acc0 = {0.f, 0.f, 0.f, 0.f}, acc1 = {0.f, 0.f, 0.f, 0.f};
#pragma unroll 4
    for (int ks = 0; ks < 16; ++ks) {
        bf16x8 a = *(const bf16x8*)(Ar + ks * 32 + q * 8);
        bf16x8 b0 = *(const bf16x8*)(bb + ks * 32);
        bf16x8 b1 = *(const bf16x8*)(bb + (size_t)16 * Nn + ks * 32);
        acc0 = MFMA(a, b0, acc0);
        acc1 = MFMA(a, b1, acc1);
    }
    float* out = Mpart + (size_t)kc * (NH * Ddim * Ddim) + (size_t)h * (Ddim * Ddim);
#pragma unroll
    for (int r = 0; r < 4; ++r) {
        int ml = q * 4 + r;
        out[(m0 + ml) * Ddim + wid * 32 + l15] = acc0[r];
        out[(m0 + ml) * Ddim + wid * 32 + 16 + l15] = acc1[r];
    }
}

// ---------------- K6b: reduce 8 K-chunks and transpose: MT[d2][h*128+d1] bf16
__global__ void k6b_mred(const float* __restrict__ Mpart, unsigned short* __restrict__ MT) {
    int idx = blockIdx.x * 256 + threadIdx.x;  // < 49152
    int d2 = idx / 384, kcol = idx % 384;
    int h = kcol >> 7, d1 = kcol & 127;
    float sum = 0.f;
#pragma unroll
    for (int kc = 0; kc < 8; ++kc)
        sum += Mpart[(size_t)kc * (NH * Ddim * Ddim) + h * (Ddim * Ddim) + d1 * Ddim + d2];
    MT[idx] = f2bf(sum);
}

// ---------------- K7: hop-merged, K-split main GEMM — unchanged from R6/R7 (measured-good).
__global__ void __launch_bounds__(256, 2) k7_fused(const void* __restrict__ adjv,
        const unsigned short* __restrict__ Yp, const float* __restrict__ dbuf,
        float* __restrict__ Pp, const float* __restrict__ mode) {
    bool isbf = mode[0] > 0.5f;
    __shared__ unsigned short Alds[2][NH][64 * 32];   // 24 KB
    __shared__ unsigned short Blds[2][NH][128 * 32];  // 48 KB
    __shared__ float dsh[NH][64];
    int b = blockIdx.x;
    int mt = b >> 3, kc = b & 7;
    int m0 = mt * 64;
    int kbase = kc * 512;
    int t = threadIdx.x;
    if (t < 192) { int h = t >> 6, m = t & 63; dsh[h][m] = dbuf[h * Nn + m0 + m]; }

    int sr = t >> 2, ss = t & 3;
    int sw = ss ^ ((sr >> 2) & 3);
    const float* aBaseF = (const float*)adjv + (size_t)(m0 + sr) * Nn + kbase + 8 * sw;
    const unsigned short* aBaseH = (const unsigned short*)adjv + (size_t)(m0 + sr) * Nn + kbase + 8 * sw;
    const unsigned short* bBase = Yp + (size_t)sr * Nn + kbase + 8 * sw;

    int wid = t >> 6, lane = t & 63, l15 = lane & 15, q = lane >> 4;
    int wm = wid >> 1, wn = wid & 1;
    f32x4 acc[NH][2][4] = {};

    float4 AF[NH][2];
    ushort8v AH[NH];
    ushort8v BR[NH][2];

    auto stage_load = [&](int c) {
        int ko = c * 32;
        if (isbf) {
#pragma unroll
            for (int h = 0; h < NH; ++h)
                AH[h] = *(const ushort8v*)(aBaseH + (size_t)h * Nn * Nn + ko);
        } else {
#pragma unroll
            for (int h = 0; h < NH; ++h) {
                AF[h][0] = *(const float4*)(aBaseF + (size_t)h * Nn * Nn + ko);
                AF[h][1] = *(const float4*)(aBaseF + (size_t)h * Nn * Nn + ko + 4);
            }
        }
#pragma unroll
        for (int h = 0; h < NH; ++h) {
            BR[h][0] = *(const ushort8v*)(bBase + (size_t)h * Ddim * Nn + ko);
            BR[h][1] = *(const ushort8v*)(bBase + (size_t)h * Ddim * Nn + (size_t)64 * Nn + ko);
        }
    };
    auto stage_write = [&](int buf) {
#pragma unroll
        for (int h = 0; h < NH; ++h) {
            ushort8v w;
            if (isbf) w = AH[h];
            else {
                w[0] = f2bf(AF[h][0].x); w[1] = f2bf(AF[h][0].y);
                w[2] = f2bf(AF[h][0].z); w[3] = f2bf(AF[h][0].w);
                w[4] = f2bf(AF[h][1].x); w[5] = f2bf(AF[h][1].y);
                w[6] = f2bf(AF[h][1].z); w[7] = f2bf(AF[h][1].w);
            }
            *(ushort8v*)&Alds[buf][h][t * 8] = w;
            *(ushort8v*)&Blds[buf][h][t * 8] = BR[h][0];
            *(ushort8v*)&Blds[buf][h][2048 + t * 8] = BR[h][1];
        }
    };
    auto compute = [&](int buf) {
#pragma unroll
        for (int h = 0; h < NH; ++h) {
            bf16x8 af[2], bfr[4];
#pragma unroll
            for (int i = 0; i < 2; ++i) {
                int m = wm * 32 + i * 16 + l15;
                af[i] = *(const bf16x8*)&Alds[buf][h][m * 32 + (q ^ ((m >> 2) & 3)) * 8];
            }
#pragma unroll
            for (int j = 0; j < 4; ++j) {
                int n = wn * 64 + j * 16 + l15;
                bfr[j] = *(const bf16x8*)&Blds[buf][h][n * 32 + (q ^ ((n >> 2) & 3)) * 8];
            }
#pragma unroll
            for (int i = 0; i < 2; ++i)
#pragma unroll
                for (int j = 0; j < 4; ++j)
                    acc[h][i][j] = MFMA(af[i], bfr[j], acc[h][i][j]);
        }
    };

    stage_load(0);
    stage_write(0);
    __syncthreads();
#pragma unroll 2
    for (int c = 0; c < 16; ++c) {
        if (c < 15) stage_load(c + 1);
        compute(c & 1);
        if (c < 15) {
            stage_write((c + 1) & 1);
            __syncthreads();
        }
    }

    float* Pk = Pp + (size_t)kc * (Nn * Ddim);
#pragma unroll
    for (int i = 0; i < 2; ++i) {
#pragma unroll
        for (int r = 0; r < 4; ++r) {
            int row = wm * 32 + i * 16 + q * 4 + r;
            float d0 = dsh[0][row], d1 = dsh[1][row], d2 = dsh[2][row];
            float* pr = Pk + (size_t)(m0 + row) * Ddim + wn * 64 + l15;
#pragma unroll
            for (int j = 0; j < 4; ++j) {
                float v = d0 * acc[0][i][j][r] + d1 * acc[1][i][j][r] + d2 * acc[2][i][j][r];
                pr[j * 16] = v;
            }
        }
    }
}

// ---------------- K9: merged k8+k9. Per 16-row tile: compute L = sum_h alpha*d_h*(E@M_h)
// in registers (12 MFMA pairs over K=384), stage L-tile through LDS to restore
// row-contiguous layout, then combine with the 8 Pp partials + relu + store.
// Removes the k8 launch and L's global round-trip.
__global__ void k9_lcombine(const float* __restrict__ E, const float* __restrict__ dbuf,
                            const void* __restrict__ alphap, const unsigned short* __restrict__ MT,
                            const float* __restrict__ Pp, void* __restrict__ outv,
                            const float* __restrict__ mode) {
    bool isbf = mode[0] > 0.5f;
    __shared__ float Ltile[16][132];  // +4 pad
    int mt = blockIdx.x;
    int t = threadIdx.x, wid = t >> 6, lane = t & 63, l15 = lane & 15, q = lane >> 4;
    int m0 = mt * 16, m = m0 + l15;
    float a = isbf ? bf2f(((const unsigned short*)alphap)[0]) : ((const float*)alphap)[0];
    float dv[NH];
#pragma unroll
    for (int h = 0; h < NH; ++h) dv[h] = a * dbuf[h * Nn + m];
    const float* Er = E + (size_t)m * Ddim;
    const unsigned short* b0p = MT + (size_t)(wid * 32 + l15) * 384;
    const unsigned short* b1p = b0p + 16 * 384;
    f32x4 acc0 = {0.f, 0.f, 0.f, 0.f}, acc1 = {0.f, 0.f, 0.f, 0.f};
#pragma unroll
    for (int ks = 0; ks < 12; ++ks) {
        int kk = ks * 32;
        int h = kk >> 7;
        int kloc = (kk & 127) + q * 8;
        bf16x8 aa = cvt8(Er + kloc, dv[h]);
        bf16x8 b0 = *(const bf16x8*)(b0p + kk + q * 8);
        bf16x8 b1 = *(const bf16x8*)(b1p + kk + q * 8);
        acc0 = MFMA(aa, b0, acc0);
        acc1 = MFMA(aa, b1, acc1);
    }
#pragma unroll
    for (int r = 0; r < 4; ++r) {
        Ltile[q * 4 + r][wid * 32 + l15] = acc0[r];
        Ltile[q * 4 + r][wid * 32 + 16 + l15] = acc1[r];
    }
    __syncthreads();
#pragma unroll
    for (int p = t; p < 512; p += 256) {
        int row = p >> 5, c4 = (p & 31) * 4;
        size_t off = (size_t)(m0 + row) * Ddim + c4;
        float4 lv = *(const float4*)&Ltile[row][c4];
        float r0 = lv.x, r1 = lv.y, r2 = lv.z, r3 = lv.w;
#pragma unroll
        for (int kc = 0; kc < 8; ++kc) {
            float4 v = *(const float4*)(Pp + (size_t)kc * (Nn * Ddim) + off);
            r0 += v.x; r1 += v.y; r2 += v.z; r3 += v.w;
        }
        r0 = r0 > 0.f ? r0 : 0.f;
        r1 = r1 > 0.f ? r1 : 0.f;
        r2 = r2 > 0.f ? r2 : 0.f;
        r3 = r3 > 0.f ? r3 : 0.f;
        if (isbf) {
            ushort4v w;
            w[0] = f2bf(r0); w[1] = f2bf(r1); w[2] = f2bf(r2); w[3] = f2bf(r3);
            *(ushort4v*)((unsigned short*)outv + off) = w;
        } else {
            float4 w; w.x = r0; w.y = r1; w.z = r2; w.w = r3;
            *(float4*)((float*)outv + off) = w;
        }
    }
}

extern "C" void kernel_launch(void* const* d_in, const int* in_sizes, int n_in,
                              void* d_out, int out_size, void* d_ws, size_t ws_size,
                              hipStream_t stream) {
    const void* X = d_in[0];
    const void* adj = d_in[1];
    const void* W_emb = d_in[2];
    const void* kernels = d_in[3];
    const void* alphap = d_in[4];

    // workspace layout (~34 MB)
    float* E = (float*)d_ws;            // 524288 f32
    float* XK = E + 524288;             // 1572864 f32
    float* rowsum = XK + 1572864;       // 12288 f32
    float* s = rowsum + 12288;          // 128 f32
    float* dbuf = s + 128;              // 12288 f32
    float* Mpart = dbuf + 12288;        // 393216 f32
    float* L = Mpart + 393216;          // 524288 f32 (unused after k8->k9 merge)
    float* Pp = L + 524288;             // 8 x 524288 f32 (K-split partials)
    unsigned short* WT = (unsigned short*)(Pp + 8 * 524288);  // 131072 u16
    unsigned short* ET = WT + 131072;   // 524288 u16
    unsigned short* Yp = ET + 524288;   // 1572864 u16  (Y^T row-major [h][128][4096])
    unsigned short* MT = Yp + 1572864;  // 49152 u16
    float* modef = (float*)(MT + 49152);// 1 f32

    k0_wt<<<8, 256, 0, stream>>>(W_emb, kernels, WT, (const unsigned short*)X, modef, s);
    k12_proj_rowsum<<<4096, 256, 0, stream>>>(X, WT, E, XK, s, adj, rowsum, modef);
    k5_transpose<<<256, 256, 0, stream>>>(XK, E, rowsum, s, alphap, dbuf, Yp, ET, modef);
    k6_mgen<<<192, 256, 0, stream>>>(ET, Yp, Mpart);
    k6b_mred<<<192, 256, 0, stream>>>(Mpart, MT);
    k7_fused<<<512, 256, 0, stream>>>(adj, Yp, dbuf, Pp, modef);
    k9_lcombine<<<256, 256, 0, stream>>>(E, dbuf, alphap, MT, Pp, d_out, modef);
}

// Round 9
// 361.759 us; speedup vs baseline: 1.3959x; 1.0083x over previous
//
#include <hip/hip_runtime.h>
#include <hip/hip_bf16.h>

#define Nn 4096
#define Fdim 256
#define Ddim 128
#define NH 3

typedef __bf16 bf16x8 __attribute__((ext_vector_type(8)));
typedef float f32x4 __attribute__((ext_vector_type(4)));
typedef unsigned short ushort8v __attribute__((ext_vector_type(8)));
typedef unsigned short ushort4v __attribute__((ext_vector_type(4)));

#define MFMA(a, b, c) __builtin_amdgcn_mfma_f32_16x16x32_bf16((a), (b), (c), 0, 0, 0)

__device__ __forceinline__ float bf2f(unsigned short u) {
    union { unsigned int i; float f; } cv;
    cv.i = ((unsigned int)u) << 16;
    return cv.f;
}
__device__ __forceinline__ unsigned short f2bf(float f) {
    union { __bf16 b; unsigned short u; } cv;
    cv.b = (__bf16)f;
    return cv.u;
}
__device__ __forceinline__ bf16x8 cvt8(const float* p, float s) {
    const float4 lo = *(const float4*)p;
    const float4 hi = *(const float4*)(p + 4);
    bf16x8 r;
    r[0] = (__bf16)(lo.x * s); r[1] = (__bf16)(lo.y * s);
    r[2] = (__bf16)(lo.z * s); r[3] = (__bf16)(lo.w * s);
    r[4] = (__bf16)(hi.x * s); r[5] = (__bf16)(hi.y * s);
    r[6] = (__bf16)(hi.z * s); r[7] = (__bf16)(hi.w * s);
    return r;
}

// ---------------- K0: W/kernels ([4][256][128] -> WT [4][128][256] bf16).
// Self-probes dtype; block 0 publishes mode[0] and zero-inits s[128].
__global__ void k0_wt(const void* __restrict__ W_emb, const void* __restrict__ kernels,
                      unsigned short* __restrict__ WT, const unsigned short* __restrict__ X,
                      float* __restrict__ mode, float* __restrict__ s) {
    __shared__ float smode;
    int b = blockIdx.x, t = threadIdx.x;
    if (t < 64) {
        int wild = 0;
        for (int i = t; i < 2048; i += 64) {
            unsigned short u = X[i];
            int e = (u >> 7) & 0xFF;
            if (e >= 132) wild = 1;
        }
        unsigned long long mba = __ballot(wild != 0);  // wave 0 fully active
        if (t == 0) smode = (__popcll(mba) > 4) ? 0.0f : 1.0f;  // 1.0 => bf16 inputs
    }
    __syncthreads();
    bool isbf = smode > 0.5f;
    if (b == 0 && t < 128) {
        s[t] = 0.f;
        if (t == 0) mode[0] = smode;
    }
    int nt = b >> 1, fh = b & 1;
    __shared__ unsigned short T[128][136];
    int d4 = t & 31, fr = t >> 5;
    if (isbf) {
        const unsigned short* Wsrc = (nt == 0) ? (const unsigned short*)W_emb
                                               : ((const unsigned short*)kernels + (size_t)(nt - 1) * Fdim * Ddim);
        for (int p = 0; p < 16; ++p) {
            int fl = fr + 8 * p;
            int f = fh * 128 + fl;
            ushort4v v = *(const ushort4v*)(Wsrc + (size_t)f * Ddim + 4 * d4);
            T[4 * d4 + 0][fl] = v[0]; T[4 * d4 + 1][fl] = v[1];
            T[4 * d4 + 2][fl] = v[2]; T[4 * d4 + 3][fl] = v[3];
        }
    } else {
        const float* Wsrc = (nt == 0) ? (const float*)W_emb
                                      : ((const float*)kernels + (size_t)(nt - 1) * Fdim * Ddim);
        for (int p = 0; p < 16; ++p) {
            int fl = fr + 8 * p;
            int f = fh * 128 + fl;
            float4 v = *(const float4*)(Wsrc + (size_t)f * Ddim + 4 * d4);
            T[4 * d4 + 0][fl] = f2bf(v.x); T[4 * d4 + 1][fl] = f2bf(v.y);
            T[4 * d4 + 2][fl] = f2bf(v.z); T[4 * d4 + 3][fl] = f2bf(v.w);
        }
    }
    __syncthreads();
    int f4 = t & 31, dr = t >> 5;
    for (int p = 0; p < 16; ++p) {
        int dd = dr + 8 * p;
        ushort4v w;
        w[0] = T[dd][4 * f4 + 0]; w[1] = T[dd][4 * f4 + 1];
        w[2] = T[dd][4 * f4 + 2]; w[3] = T[dd][4 * f4 + 3];
        *(ushort4v*)(WT + (size_t)nt * Ddim * Fdim + (size_t)dd * Fdim + fh * 128 + 4 * f4) = w;
    }
}

// ---------------- K12: merged projection + adj rowsum (independent work, one dispatch).
__global__ void k12_proj_rowsum(const void* __restrict__ Xv, const unsigned short* __restrict__ WT,
                                float* __restrict__ E, float* __restrict__ XK, float* __restrict__ s,
                                const void* __restrict__ adjv, float* __restrict__ rowsum,
                                const float* __restrict__ mode) {
    bool isbf = mode[0] > 0.5f;
    int b = blockIdx.x;
    int t = threadIdx.x;
    if (b < 1024) {
        int mt = b >> 2, nt = b & 3;
        int wid = t >> 6, lane = t & 63, l15 = lane & 15, q = lane >> 4;
        int m0 = mt * 16;
        const unsigned short* BT = WT + (size_t)nt * Ddim * Fdim;
        const unsigned short* b0p = BT + (size_t)(wid * 32 + l15) * Fdim;
        const unsigned short* b1p = b0p + 16 * Fdim;
        f32x4 acc0 = {0.f, 0.f, 0.f, 0.f}, acc1 = {0.f, 0.f, 0.f, 0.f};
        if (isbf) {
            const unsigned short* Arow = (const unsigned short*)Xv + (size_t)(m0 + l15) * Fdim;
#pragma unroll
            for (int ks = 0; ks < 8; ++ks) {
                int kk = ks * 32 + q * 8;
                bf16x8 a = *(const bf16x8*)(Arow + kk);
                bf16x8 b0 = *(const bf16x8*)(b0p + kk);
                bf16x8 b1 = *(const bf16x8*)(b1p + kk);
                acc0 = MFMA(a, b0, acc0);
                acc1 = MFMA(a, b1, acc1);
            }
        } else {
            const float* Arow = (const float*)Xv + (size_t)(m0 + l15) * Fdim;
#pragma unroll
            for (int ks = 0; ks < 8; ++ks) {
                int kk = ks * 32 + q * 8;
                bf16x8 a = cvt8(Arow + kk, 1.0f);
                bf16x8 b0 = *(const bf16x8*)(b0p + kk);
                bf16x8 b1 = *(const bf16x8*)(b1p + kk);
                acc0 = MFMA(a, b0, acc0);
                acc1 = MFMA(a, b1, acc1);
            }
        }
        float* dst = (nt == 0) ? E : (XK + (size_t)(nt - 1) * Nn * Ddim);
#pragma unroll
        for (int r = 0; r < 4; ++r) {
            int ml = q * 4 + r;
            dst[(size_t)(m0 + ml) * Ddim + wid * 32 + l15] = acc0[r];
            dst[(size_t)(m0 + ml) * Ddim + wid * 32 + 16 + l15] = acc1[r];
        }
        if (nt == 0) {
            float c0 = acc0[0] + acc0[1] + acc0[2] + acc0[3];
            float c1 = acc1[0] + acc1[1] + acc1[2] + acc1[3];
            c0 += __shfl_xor(c0, 16, 64); c0 += __shfl_xor(c0, 32, 64);
            c1 += __shfl_xor(c1, 16, 64); c1 += __shfl_xor(c1, 32, 64);
            if (q == 0) {
                atomicAdd(&s[wid * 32 + l15], c0);
                atomicAdd(&s[wid * 32 + 16 + l15], c1);
            }
        }
    } else {
        int w = t >> 6, lane = t & 63;
        int r = (b - 1024) * 4 + w;
        float sum = 0.f;
        if (isbf) {
            const unsigned short* rp = (const unsigned short*)adjv + (size_t)r * Nn;
#pragma unroll
            for (int it = 0; it < 8; ++it) {
                ushort8v v = *(const ushort8v*)(rp + (it * 64 + lane) * 8);
                sum += bf2f(v[0]) + bf2f(v[1]) + bf2f(v[2]) + bf2f(v[3]) +
                       bf2f(v[4]) + bf2f(v[5]) + bf2f(v[6]) + bf2f(v[7]);
            }
        } else {
            const float4* rp = (const float4*)((const float*)adjv + (size_t)r * Nn);
#pragma unroll
            for (int it = 0; it < 16; ++it) {
                float4 v = rp[it * 64 + lane];
                sum += v.x + v.y + v.z + v.w;
            }
        }
#pragma unroll
        for (int off = 32; off > 0; off >>= 1) sum += __shfl_down(sum, off, 64);
        if (lane == 0) rowsum[r] = sum;
    }
}

// ---------------- K5: build Y^T[h][n][j] = bf16(d_h[j]*XK[h][j][n]) row-major [128][4096]
// and row-major ET[d][j] = bf16(E[j][d]). Y blocks also generate d (replaces k4).
__global__ void k5_transpose(const float* __restrict__ XK, const float* __restrict__ E,
                             const float* __restrict__ rowsum, const float* __restrict__ s,
                             const void* __restrict__ alphap, float* __restrict__ dbuf,
                             unsigned short* __restrict__ Yp, unsigned short* __restrict__ ET,
                             const float* __restrict__ mode) {
    bool isbf = mode[0] > 0.5f;
    __shared__ unsigned short T[128][72];
    __shared__ float sl[64];
    __shared__ float ss[128];
    int b = blockIdx.x, t = threadIdx.x;
    bool isET = (b >= 192);
    int h = 0, jt;
    const float* src;
    if (!isET) { h = b >> 6; jt = b & 63; src = XK + (size_t)h * Nn * Ddim; }
    else { jt = b - 192; src = E; }
    if (isET) {
        if (t < 64) sl[t] = 1.0f;
    } else {
        if (t < 128) ss[t] = s[t];
        __syncthreads();
        int node = t >> 2, sub = t & 3;
        int gn = jt * 64 + node;
        const float4* er = (const float4*)(E + (size_t)gn * Ddim + sub * 32);
        float acc = 0.f;
#pragma unroll
        for (int k = 0; k < 8; ++k) {
            float4 v = er[k];
            int c = sub * 32 + 4 * k;
            acc += v.x * ss[c] + v.y * ss[c + 1] + v.z * ss[c + 2] + v.w * ss[c + 3];
        }
        acc += __shfl_xor(acc, 1, 64);
        acc += __shfl_xor(acc, 2, 64);
        if (sub == 0) {
            float a = isbf ? bf2f(((const unsigned short*)alphap)[0]) : ((const float*)alphap)[0];
            float d = rsqrtf(rowsum[h * Nn + gn] + a * acc);
            sl[node] = d;
            dbuf[h * Nn + gn] = d;
        }
    }
    __syncthreads();
    int d4 = t & 31, jr = t >> 5;
    for (int p = 0; p < 8; ++p) {
        int j = jr + 8 * p;  // 0..63
        float4 v = *(const float4*)(src + (size_t)(jt * 64 + j) * Ddim + 4 * d4);
        float sc = sl[j];
        T[4 * d4 + 0][j] = f2bf(v.x * sc); T[4 * d4 + 1][j] = f2bf(v.y * sc);
        T[4 * d4 + 2][j] = f2bf(v.z * sc); T[4 * d4 + 3][j] = f2bf(v.w * sc);
    }
    __syncthreads();
    int jj4 = t & 15, nr = t >> 4;
    unsigned short* dst = isET ? ET : (Yp + (size_t)h * Ddim * Nn);
    for (int p = 0; p < 8; ++p) {
        int n = nr + 16 * p;  // 0..127
        ushort4v w;
        w[0] = T[n][4 * jj4 + 0]; w[1] = T[n][4 * jj4 + 1];
        w[2] = T[n][4 * jj4 + 2]; w[3] = T[n][4 * jj4 + 3];
        int j = jt * 64 + 4 * jj4;
        *(ushort4v*)(dst + (size_t)n * Nn + j) = w;
    }
}

// ---------------- K7+K6 merged dispatch: both consume only k5's outputs (independent).
// Blocks 0..511: hop-merged K-split main GEMM (unchanged R6/R7 structure, 2 blocks/CU).
// Blocks 512..703: k6's Mpart[kc][h] = (E^T @ Y_h) — MFMA/L2-bound waves that fill
// CU slots while k7 blocks sit at their barrier vmcnt drains (k12-validated pattern).
__global__ void __launch_bounds__(256, 2) k7_fused(const void* __restrict__ adjv,
        const unsigned short* __restrict__ Yp, const float* __restrict__ dbuf,
        float* __restrict__ Pp, const unsigned short* __restrict__ ET,
        float* __restrict__ Mpart, const float* __restrict__ mode) {
    bool isbf = mode[0] > 0.5f;
    __shared__ unsigned short Alds[2][NH][64 * 32];   // 24 KB
    __shared__ unsigned short Blds[2][NH][128 * 32];  // 48 KB
    __shared__ float dsh[NH][64];
    int b = blockIdx.x;
    int t = threadIdx.x;
    int wid = t >> 6, lane = t & 63, l15 = lane & 15, q = lane >> 4;

    if (b >= 512) {
        // ---- k6 part: Mpart[kc][h] = (E^T @ Y_h) partial over K-chunk
        int bb = b - 512;
        int kc = bb / 24, rem = bb % 24, h = rem >> 3, mtm = rem & 7;
        int m0 = mtm * 16;
        const unsigned short* Ar = ET + (size_t)(m0 + l15) * Nn + kc * 512;
        const unsigned short* Yph = Yp + (size_t)h * Ddim * Nn;
        const unsigned short* bbp = Yph + (size_t)(wid * 32 + l15) * Nn + kc * 512 + q * 8;
        f32x4 acc0 = {0.f, 0.f, 0.f, 0.f}, acc1 = {0.f, 0.f, 0.f, 0.f};
#pragma unroll 4
        for (int ks = 0; ks < 16; ++ks) {
            bf16x8 a = *(const bf16x8*)(Ar + ks * 32 + q * 8);
            bf16x8 b0 = *(const bf16x8*)(bbp + ks * 32);
            bf16x8 b1 = *(const bf16x8*)(bbp + (size_t)16 * Nn + ks * 32);
            acc0 = MFMA(a, b0, acc0);
            acc1 = MFMA(a, b1, acc1);
        }
        float* out = Mpart + (size_t)kc * (NH * Ddim * Ddim) + (size_t)h * (Ddim * Ddim);
#pragma unroll
        for (int r = 0; r < 4; ++r) {
            int ml = q * 4 + r;
            out[(m0 + ml) * Ddim + wid * 32 + l15] = acc0[r];
            out[(m0 + ml) * Ddim + wid * 32 + 16 + l15] = acc1[r];
        }
        return;
    }

    // ---- k7 part
    int mt = b >> 3, kc = b & 7;
    int m0 = mt * 64;
    int kbase = kc * 512;
    if (t < 192) { int h = t >> 6, m = t & 63; dsh[h][m] = dbuf[h * Nn + m0 + m]; }

    int sr = t >> 2, ss = t & 3;
    int sw = ss ^ ((sr >> 2) & 3);
    const float* aBaseF = (const float*)adjv + (size_t)(m0 + sr) * Nn + kbase + 8 * sw;
    const unsigned short* aBaseH = (const unsigned short*)adjv + (size_t)(m0 + sr) * Nn + kbase + 8 * sw;
    const unsigned short* bBase = Yp + (size_t)sr * Nn + kbase + 8 * sw;

    int wm = wid >> 1, wn = wid & 1;
    f32x4 acc[NH][2][4] = {};

    float4 AF[NH][2];
    ushort8v AH[NH];
    ushort8v BR[NH][2];

    auto stage_load = [&](int c) {
        int ko = c * 32;
        if (isbf) {
#pragma unroll
            for (int h = 0; h < NH; ++h)
                AH[h] = *(const ushort8v*)(aBaseH + (size_t)h * Nn * Nn + ko);
        } else {
#pragma unroll
            for (int h = 0; h < NH; ++h) {
                AF[h][0] = *(const float4*)(aBaseF + (size_t)h * Nn * Nn + ko);
                AF[h][1] = *(const float4*)(aBaseF + (size_t)h * Nn * Nn + ko + 4);
            }
        }
#pragma unroll
        for (int h = 0; h < NH; ++h) {
            BR[h][0] = *(const ushort8v*)(bBase + (size_t)h * Ddim * Nn + ko);
            BR[h][1] = *(const ushort8v*)(bBase + (size_t)h * Ddim * Nn + (size_t)64 * Nn + ko);
        }
    };
    auto stage_write = [&](int buf) {
#pragma unroll
        for (int h = 0; h < NH; ++h) {
            ushort8v w;
            if (isbf) w = AH[h];
            else {
                w[0] = f2bf(AF[h][0].x); w[1] = f2bf(AF[h][0].y);
                w[2] = f2bf(AF[h][0].z); w[3] = f2bf(AF[h][0].w);
                w[4] = f2bf(AF[h][1].x); w[5] = f2bf(AF[h][1].y);
                w[6] = f2bf(AF[h][1].z); w[7] = f2bf(AF[h][1].w);
            }
            *(ushort8v*)&Alds[buf][h][t * 8] = w;
            *(ushort8v*)&Blds[buf][h][t * 8] = BR[h][0];
            *(ushort8v*)&Blds[buf][h][2048 + t * 8] = BR[h][1];
        }
    };
    auto compute = [&](int buf) {
#pragma unroll
        for (int h = 0; h < NH; ++h) {
            bf16x8 af[2], bfr[4];
#pragma unroll
            for (int i = 0; i < 2; ++i) {
                int m = wm * 32 + i * 16 + l15;
                af[i] = *(const bf16x8*)&Alds[buf][h][m * 32 + (q ^ ((m >> 2) & 3)) * 8];
            }
#pragma unroll
            for (int j = 0; j < 4; ++j) {
                int n = wn * 64 + j * 16 + l15;
                bfr[j] = *(const bf16x8*)&Blds[buf][h][n * 32 + (q ^ ((n >> 2) & 3)) * 8];
            }
#pragma unroll
            for (int i = 0; i < 2; ++i)
#pragma unroll
                for (int j = 0; j < 4; ++j)
                    acc[h][i][j] = MFMA(af[i], bfr[j], acc[h][i][j]);
        }
    };

    stage_load(0);
    stage_write(0);
    __syncthreads();
#pragma unroll 2
    for (int c = 0; c < 16; ++c) {
        if (c < 15) stage_load(c + 1);
        compute(c & 1);
        if (c < 15) {
            stage_write((c + 1) & 1);
            __syncthreads();
        }
    }

    float* Pk = Pp + (size_t)kc * (Nn * Ddim);
#pragma unroll
    for (int i = 0; i < 2; ++i) {
#pragma unroll
        for (int r = 0; r < 4; ++r) {
            int row = wm * 32 + i * 16 + q * 4 + r;
            float d0 = dsh[0][row], d1 = dsh[1][row], d2 = dsh[2][row];
            float* pr = Pk + (size_t)(m0 + row) * Ddim + wn * 64 + l15;
#pragma unroll
            for (int j = 0; j < 4; ++j) {
                float v = d0 * acc[0][i][j][r] + d1 * acc[1][i][j][r] + d2 * acc[2][i][j][r];
                pr[j * 16] = v;
            }
        }
    }
}

// ---------------- K6b: reduce 8 K-chunks and transpose: MT[d2][h*128+d1] bf16
__global__ void k6b_mred(const float* __restrict__ Mpart, unsigned short* __restrict__ MT) {
    int idx = blockIdx.x * 256 + threadIdx.x;  // < 49152
    int d2 = idx / 384, kcol = idx % 384;
    int h = kcol >> 7, d1 = kcol & 127;
    float sum = 0.f;
#pragma unroll
    for (int kc = 0; kc < 8; ++kc)
        sum += Mpart[(size_t)kc * (NH * Ddim * Ddim) + h * (Ddim * Ddim) + d1 * Ddim + d2];
    MT[idx] = f2bf(sum);
}

// ---------------- K9: merged k8+k9. Per 16-row tile: compute L in registers (12 MFMA
// pairs over K=384), stage through LDS, combine with the 8 Pp partials + relu + store.
__global__ void k9_lcombine(const float* __restrict__ E, const float* __restrict__ dbuf,
                            const void* __restrict__ alphap, const unsigned short* __restrict__ MT,
                            const float* __restrict__ Pp, void* __restrict__ outv,
                            const float* __restrict__ mode) {
    bool isbf = mode[0] > 0.5f;
    __shared__ float Ltile[16][132];  // +4 pad
    int mt = blockIdx.x;
    int t = threadIdx.x, wid = t >> 6, lane = t & 63, l15 = lane & 15, q = lane >> 4;
    int m0 = mt * 16, m = m0 + l15;
    float a = isbf ? bf2f(((const unsigned short*)alphap)[0]) : ((const float*)alphap)[0];
    float dv[NH];
#pragma unroll
    for (int h = 0; h < NH; ++h) dv[h] = a * dbuf[h * Nn + m];
    const float* Er = E + (size_t)m * Ddim;
    const unsigned short* b0p = MT + (size_t)(wid * 32 + l15) * 384;
    const unsigned short* b1p = b0p + 16 * 384;
    f32x4 acc0 = {0.f, 0.f, 0.f, 0.f}, acc1 = {0.f, 0.f, 0.f, 0.f};
#pragma unroll
    for (int ks = 0; ks < 12; ++ks) {
        int kk = ks * 32;
        int h = kk >> 7;
        int kloc = (kk & 127) + q * 8;
        bf16x8 aa = cvt8(Er + kloc, dv[h]);
        bf16x8 b0 = *(const bf16x8*)(b0p + kk + q * 8);
        bf16x8 b1 = *(const bf16x8*)(b1p + kk + q * 8);
        acc0 = MFMA(aa, b0, acc0);
        acc1 = MFMA(aa, b1, acc1);
    }
#pragma unroll
    for (int r = 0; r < 4; ++r) {
        Ltile[q * 4 + r][wid * 32 + l15] = acc0[r];
        Ltile[q * 4 + r][wid * 32 + 16 + l15] = acc1[r];
    }
    __syncthreads();
#pragma unroll
    for (int p = t; p < 512; p += 256) {
        int row = p >> 5, c4 = (p & 31) * 4;
        size_t off = (size_t)(m0 + row) * Ddim + c4;
        float4 lv = *(const float4*)&Ltile[row][c4];
        float r0 = lv.x, r1 = lv.y, r2 = lv.z, r3 = lv.w;
#pragma unroll
        for (int kc = 0; kc < 8; ++kc) {
            float4 v = *(const float4*)(Pp + (size_t)kc * (Nn * Ddim) + off);
            r0 += v.x; r1 += v.y; r2 += v.z; r3 += v.w;
        }
        r0 = r0 > 0.f ? r0 : 0.f;
        r1 = r1 > 0.f ? r1 : 0.f;
        r2 = r2 > 0.f ? r2 : 0.f;
        r3 = r3 > 0.f ? r3 : 0.f;
        if (isbf) {
            ushort4v w;
            w[0] = f2bf(r0); w[1] = f2bf(r1); w[2] = f2bf(r2); w[3] = f2bf(r3);
            *(ushort4v*)((unsigned short*)outv + off) = w;
        } else {
            float4 w; w.x = r0; w.y = r1; w.z = r2; w.w = r3;
            *(float4*)((float*)outv + off) = w;
        }
    }
}

extern "C" void kernel_launch(void* const* d_in, const int* in_sizes, int n_in,
                              void* d_out, int out_size, void* d_ws, size_t ws_size,
                              hipStream_t stream) {
    const void* X = d_in[0];
    const void* adj = d_in[1];
    const void* W_emb = d_in[2];
    const void* kernels = d_in[3];
    const void* alphap = d_in[4];

    // workspace layout (~34 MB)
    float* E = (float*)d_ws;            // 524288 f32
    float* XK = E + 524288;             // 1572864 f32
    float* rowsum = XK + 1572864;       // 12288 f32
    float* s = rowsum + 12288;          // 128 f32
    float* dbuf = s + 128;              // 12288 f32
    float* Mpart = dbuf + 12288;        // 393216 f32
    float* L = Mpart + 393216;          // 524288 f32 (unused)
    float* Pp = L + 524288;             // 8 x 524288 f32 (K-split partials)
    unsigned short* WT = (unsigned short*)(Pp + 8 * 524288);  // 131072 u16
    unsigned short* ET = WT + 131072;   // 524288 u16
    unsigned short* Yp = ET + 524288;   // 1572864 u16  (Y^T row-major [h][128][4096])
    unsigned short* MT = Yp + 1572864;  // 49152 u16
    float* modef = (float*)(MT + 49152);// 1 f32

    k0_wt<<<8, 256, 0, stream>>>(W_emb, kernels, WT, (const unsigned short*)X, modef, s);
    k12_proj_rowsum<<<4096, 256, 0, stream>>>(X, WT, E, XK, s, adj, rowsum, modef);
    k5_transpose<<<256, 256, 0, stream>>>(XK, E, rowsum, s, alphap, dbuf, Yp, ET, modef);
    // k7+k6 merged right after k5: adj still L3-warm from k12's sweep (only k5's
    // ~38 MB in between), and k6's MFMA waves fill k7's barrier-drain idle slots.
    k7_fused<<<704, 256, 0, stream>>>(adj, Yp, dbuf, Pp, ET, Mpart, modef);
    k6b_mred<<<192, 256, 0, stream>>>(Mpart, MT);
    k9_lcombine<<<256, 256, 0, stream>>>(E, dbuf, alphap, MT, Pp, d_out, modef);
}